// Round 1
// baseline (4760.779 us; speedup 1.0000x reference)
//
#include <hip/hip_runtime.h>
#include <math.h>

#define B_ 4
#define L_ 2048
#define D_ 768
#define H_ 12
#define DH_ 64
#define F_ 3072
#define KTOP 307
#define LN_EPS 1e-5f

// ---------------- block reduce helper (256 threads, 4 waves) ----------------
__device__ __forceinline__ float blk_reduce_sum(float v, float* red) {
    #pragma unroll
    for (int off = 32; off; off >>= 1) v += __shfl_xor(v, off, 64);
    __syncthreads();
    if ((threadIdx.x & 63) == 0) red[threadIdx.x >> 6] = v;
    __syncthreads();
    return red[0] + red[1] + red[2] + red[3];
}

// ---------------- LN (+ optional router score) ----------------
// grid = B*L blocks, 256 threads; each token row of 768 = 3 elems/thread
template <bool SCORE>
__global__ __launch_bounds__(256) void ln_kernel(
    const float* __restrict__ x, const float* __restrict__ g,
    const float* __restrict__ be, const float* __restrict__ Wr,
    const float* __restrict__ brp, float* __restrict__ outn,
    float* __restrict__ scores)
{
    __shared__ float red[4];
    const int t = blockIdx.x;
    const int tid = threadIdx.x;
    const float* xr = x + (size_t)t * D_;
    float v0 = xr[tid], v1 = xr[tid + 256], v2 = xr[tid + 512];
    float mean = blk_reduce_sum(v0 + v1 + v2, red) * (1.0f / 768.0f);
    float d0 = v0 - mean, d1 = v1 - mean, d2 = v2 - mean;
    __syncthreads();
    float var = blk_reduce_sum(d0 * d0 + d1 * d1 + d2 * d2, red) * (1.0f / 768.0f);
    float inv = 1.0f / sqrtf(var + LN_EPS);
    float n0 = d0 * inv * g[tid] + be[tid];
    float n1 = d1 * inv * g[tid + 256] + be[tid + 256];
    float n2 = d2 * inv * g[tid + 512] + be[tid + 512];
    float* orow = outn + (size_t)t * D_;
    orow[tid] = n0; orow[tid + 256] = n1; orow[tid + 512] = n2;
    if (SCORE) {
        __syncthreads();
        float dot = blk_reduce_sum(n0 * Wr[tid] + n1 * Wr[tid + 256] + n2 * Wr[tid + 512], red);
        if (tid == 0) scores[t] = 1.0f / (1.0f + expf(-(dot + brp[0])));
    }
}

// ---------------- top-k (lowest K scores) + score-sum, per batch ----------------
// grid = B blocks, 256 threads; bitonic sort of 2048 (score,idx) keys
__global__ __launch_bounds__(256) void topk_kernel(
    const float* __restrict__ scores, unsigned* __restrict__ mask,
    float* __restrict__ ssum)
{
    __shared__ unsigned long long keys[L_];
    __shared__ float red[4];
    const int b = blockIdx.x, tid = threadIdx.x;
    float local = 0.f;
    for (int i = tid; i < L_; i += 256) {
        float sc = scores[b * L_ + i];
        keys[i] = ((unsigned long long)__float_as_uint(sc) << 32) | (unsigned)i;
        local += sc;
    }
    float tot = blk_reduce_sum(local, red);  // includes syncthreads
    if (tid == 0) ssum[b] = tot;
    __syncthreads();
    for (int size = 2; size <= L_; size <<= 1) {
        for (int stride = size >> 1; stride > 0; stride >>= 1) {
            for (int i = tid; i < L_; i += 256) {
                int j = i ^ stride;
                if (j > i) {
                    bool up = ((i & size) == 0);
                    unsigned long long a = keys[i], c = keys[j];
                    if ((a > c) == up) { keys[i] = c; keys[j] = a; }
                }
            }
            __syncthreads();
        }
    }
    unsigned long long cutoff = keys[KTOP - 1];
    for (int i = tid; i < L_; i += 256) {
        float sc = scores[b * L_ + i];
        unsigned long long k = ((unsigned long long)__float_as_uint(sc) << 32) | (unsigned)i;
        mask[b * L_ + i] = (k <= cutoff) ? 1u : 0u;
    }
}

// ---------------- coherence-weighted pooling ----------------
// grid = (3, B), 256 threads; pooled[b][d] = sum_l w[l]*normed[b][l][d]
__global__ __launch_bounds__(256) void pooled_kernel(
    const float* __restrict__ scores, const float* __restrict__ normed,
    const float* __restrict__ ssum, float* __restrict__ pooled)
{
    const int b = blockIdx.y;
    const int d = blockIdx.x * 256 + threadIdx.x;
    const float* np_ = normed + (size_t)b * L_ * D_ + d;
    const float* sp = scores + b * L_;
    float acc = 0.f;
    #pragma unroll 8
    for (int l = 0; l < L_; l++) acc += sp[l] * np_[(size_t)l * D_];
    pooled[b * D_ + d] = acc / (ssum[b] + 1e-6f);
}

// ---------------- generic fp32 GEMM:  C = epi(A @ W + bias) ----------------
// EPI: 0 = store, 1 = gelu store, 2 = accumulate into C
// AMODE: 0 = plain A, 1 = A[t][k] + scores[t]*pooled[b][k]  (mix path)
__device__ __forceinline__ float gelu_exact(float v) {
    return 0.5f * v * (1.0f + erff(v * 0.70710678118654752f));
}

template <int EPI, int AMODE>
__global__ __launch_bounds__(256) void gemm_kernel(
    const float* __restrict__ A, const float* __restrict__ Wt,
    const float* __restrict__ bias, float* __restrict__ C,
    int M, int N, int K,
    const float* __restrict__ scores, const float* __restrict__ pooled)
{
    __shared__ float As[16][68];
    __shared__ float Bs[16][64];
    const int tid = threadIdx.x;
    const int row0 = blockIdx.y * 64, col0 = blockIdx.x * 64;
    const int ar = tid >> 2, ac = (tid & 3) << 2;   // A stage: 64 rows x 4 floats
    const int wr = tid >> 4, wc = (tid & 15) << 2;  // W stage: 16 rows x 4 floats
    const int ty = tid >> 4, tx = tid & 15;
    const int r0 = ty * 4, c0 = tx * 4;
    float acc[4][4] = {};

    for (int k0 = 0; k0 < K; k0 += 16) {
        float4 av = *(const float4*)&A[(size_t)(row0 + ar) * K + k0 + ac];
        if (AMODE == 1) {
            int grow = row0 + ar;
            float s = scores[grow];
            float4 pv = *(const float4*)&pooled[(size_t)(grow >> 11) * D_ + k0 + ac];
            av.x += s * pv.x; av.y += s * pv.y; av.z += s * pv.z; av.w += s * pv.w;
        }
        float4 wv = *(const float4*)&Wt[(size_t)(k0 + wr) * N + col0 + wc];
        __syncthreads();
        As[ac + 0][ar] = av.x; As[ac + 1][ar] = av.y;
        As[ac + 2][ar] = av.z; As[ac + 3][ar] = av.w;
        *(float4*)&Bs[wr][wc] = wv;
        __syncthreads();
        #pragma unroll
        for (int kk = 0; kk < 16; kk++) {
            float4 a = *(const float4*)&As[kk][r0];
            float4 bv = *(const float4*)&Bs[kk][c0];
            acc[0][0] += a.x * bv.x; acc[0][1] += a.x * bv.y; acc[0][2] += a.x * bv.z; acc[0][3] += a.x * bv.w;
            acc[1][0] += a.y * bv.x; acc[1][1] += a.y * bv.y; acc[1][2] += a.y * bv.z; acc[1][3] += a.y * bv.w;
            acc[2][0] += a.z * bv.x; acc[2][1] += a.z * bv.y; acc[2][2] += a.z * bv.z; acc[2][3] += a.z * bv.w;
            acc[3][0] += a.w * bv.x; acc[3][1] += a.w * bv.y; acc[3][2] += a.w * bv.z; acc[3][3] += a.w * bv.w;
        }
    }

    const float4 b4 = *(const float4*)&bias[col0 + c0];
    #pragma unroll
    for (int i = 0; i < 4; i++) {
        size_t off = (size_t)(row0 + r0 + i) * N + col0 + c0;
        float4 val;
        val.x = acc[i][0] + b4.x; val.y = acc[i][1] + b4.y;
        val.z = acc[i][2] + b4.z; val.w = acc[i][3] + b4.w;
        if (EPI == 1) {
            val.x = gelu_exact(val.x); val.y = gelu_exact(val.y);
            val.z = gelu_exact(val.z); val.w = gelu_exact(val.w);
        }
        if (EPI == 2) {
            float4 old = *(const float4*)&C[off];
            val.x += old.x; val.y += old.y; val.z += old.z; val.w += old.w;
        }
        *(float4*)&C[off] = val;
    }
}

// ---------------- dense flash attention (fp32) ----------------
// grid = (L/256, H, B), 256 threads; each thread owns one q row
__global__ __launch_bounds__(256) void attn_kernel(
    const float* __restrict__ q, const float* __restrict__ k,
    const float* __restrict__ v, float* __restrict__ ctx)
{
    __shared__ float Ks[64][64];
    __shared__ float Vs[64][64];
    const int qi = blockIdx.x * 256 + threadIdx.x;
    const int h = blockIdx.y, b = blockIdx.z;
    const int tid = threadIdx.x;
    const float SHIFT = 12.0f;

    float4 q4[16];
    const float* qrow = q + ((size_t)(b * L_ + qi)) * D_ + h * DH_;
    #pragma unroll
    for (int dd = 0; dd < 16; dd++) {
        float4 t = *(const float4*)&qrow[dd * 4];
        q4[dd].x = t.x * 0.125f; q4[dd].y = t.y * 0.125f;
        q4[dd].z = t.z * 0.125f; q4[dd].w = t.w * 0.125f;
    }
    float4 acc4[16];
    #pragma unroll
    for (int dd = 0; dd < 16; dd++) acc4[dd] = make_float4(0.f, 0.f, 0.f, 0.f);
    float l_i = 0.f;

    const int lr = tid >> 2;            // 0..63: tile row this thread stages
    const int lc = (tid & 3) << 2;      // 0,4,8,12
    for (int mt = 0; mt < L_; mt += 64) {
        __syncthreads();
        const float* kro = k + ((size_t)(b * L_ + mt + lr)) * D_ + h * DH_;
        const float* vro = v + ((size_t)(b * L_ + mt + lr)) * D_ + h * DH_;
        #pragma unroll
        for (int i = 0; i < 4; i++) {
            int c = lc + i * 16;
            *(float4*)&Ks[lr][c] = *(const float4*)&kro[c];
            *(float4*)&Vs[lr][c] = *(const float4*)&vro[c];
        }
        __syncthreads();
        for (int j = 0; j < 64; ++j) {
            const float4* kr = (const float4*)&Ks[j][0];
            float s0 = 0.f, s1 = 0.f, s2 = 0.f, s3 = 0.f;
            #pragma unroll
            for (int dd = 0; dd < 16; dd++) {
                float4 kv = kr[dd];
                s0 += q4[dd].x * kv.x; s1 += q4[dd].y * kv.y;
                s2 += q4[dd].z * kv.z; s3 += q4[dd].w * kv.w;
            }
            float p = expf((s0 + s1) + (s2 + s3) - SHIFT);
            l_i += p;
            const float4* vr = (const float4*)&Vs[j][0];
            #pragma unroll
            for (int dd = 0; dd < 16; dd++) {
                float4 vv = vr[dd];
                acc4[dd].x += p * vv.x; acc4[dd].y += p * vv.y;
                acc4[dd].z += p * vv.z; acc4[dd].w += p * vv.w;
            }
        }
    }
    float inv = 1.0f / l_i;
    float* crow = ctx + ((size_t)(b * L_ + qi)) * D_ + h * DH_;
    #pragma unroll
    for (int dd = 0; dd < 16; dd++) {
        float4 o;
        o.x = acc4[dd].x * inv; o.y = acc4[dd].y * inv;
        o.z = acc4[dd].z * inv; o.w = acc4[dd].w * inv;
        *(float4*)&crow[dd * 4] = o;
    }
}

// ---------------- merge: h = x + (mask ? attn : mix); also prefill out=h ----------
// grid = (B*L, 3), 256 threads
__global__ __launch_bounds__(256) void merge_kernel(
    const float* __restrict__ x, const unsigned* __restrict__ mask,
    const float* __restrict__ attn, const float* __restrict__ mix,
    float* __restrict__ h, float* __restrict__ out)
{
    const int t = blockIdx.x;
    const int d = blockIdx.y * 256 + threadIdx.x;
    size_t idx = (size_t)t * D_ + d;
    float val = x[idx] + (mask[t] ? attn[idx] : mix[idx]);
    h[idx] = val;
    out[idx] = val;
}

// ---------------- launch ----------------
extern "C" void kernel_launch(void* const* d_in, const int* in_sizes, int n_in,
                              void* d_out, int out_size, void* d_ws, size_t ws_size,
                              hipStream_t stream)
{
    const float* x   = (const float*)d_in[0];
    const float* g1  = (const float*)d_in[1];
    const float* b1  = (const float*)d_in[2];
    const float* g2  = (const float*)d_in[3];
    const float* b2  = (const float*)d_in[4];
    const float* Wr  = (const float*)d_in[5];
    const float* br  = (const float*)d_in[6];
    const float* Wq  = (const float*)d_in[7];
    const float* bq  = (const float*)d_in[8];
    const float* Wk  = (const float*)d_in[9];
    const float* bk  = (const float*)d_in[10];
    const float* Wv  = (const float*)d_in[11];
    const float* bv  = (const float*)d_in[12];
    const float* Wo  = (const float*)d_in[13];
    const float* bo  = (const float*)d_in[14];
    const float* Wm  = (const float*)d_in[15];
    const float* bm  = (const float*)d_in[16];
    const float* W1  = (const float*)d_in[17];
    const float* bf1 = (const float*)d_in[18];
    const float* W2  = (const float*)d_in[19];
    const float* bf2 = (const float*)d_in[20];
    float* out = (float*)d_out;

    float* W = (float*)d_ws;
    const size_t SZ = (size_t)B_ * L_ * D_;  // 6291456 floats
    float* S0 = W;            // normed (kept for mix path), later ffn-mid chunks
    float* S1 = W + SZ;       // q -> attn_out
    float* S2 = W + 2 * SZ;   // k -> mix_out
    float* S3 = W + 3 * SZ;   // v -> h
    float* S4 = W + 4 * SZ;   // ctx -> n2
    float* scores = W + 5 * SZ;
    float* ssum   = scores + B_ * L_;
    float* pooled = ssum + 8;
    unsigned* mask = (unsigned*)(pooled + B_ * D_);

    const int NT = B_ * L_;  // 8192 tokens

    // 1. LN1 + router scores
    ln_kernel<true><<<NT, 256, 0, stream>>>(x, g1, b1, Wr, br, S0, scores);
    // 2. top-k mask + score sums
    topk_kernel<<<B_, 256, 0, stream>>>(scores, mask, ssum);
    // 3. pooled
    pooled_kernel<<<dim3(3, B_), 256, 0, stream>>>(scores, S0, ssum, pooled);
    // 4-6. QKV projections
    gemm_kernel<0, 0><<<dim3(12, 128), 256, 0, stream>>>(S0, Wq, bq, S1, NT, D_, D_, nullptr, nullptr);
    gemm_kernel<0, 0><<<dim3(12, 128), 256, 0, stream>>>(S0, Wk, bk, S2, NT, D_, D_, nullptr, nullptr);
    gemm_kernel<0, 0><<<dim3(12, 128), 256, 0, stream>>>(S0, Wv, bv, S3, NT, D_, D_, nullptr, nullptr);
    // 7. attention -> ctx (S4)
    attn_kernel<<<dim3(L_ / 256, H_, B_), 256, 0, stream>>>(S1, S2, S3, S4);
    // 8. attn_out = ctx @ Wo + bo  -> S1
    gemm_kernel<0, 0><<<dim3(12, 128), 256, 0, stream>>>(S4, Wo, bo, S1, NT, D_, D_, nullptr, nullptr);
    // 9. mix_out = (normed + s*pooled) @ Wm + bm -> S2
    gemm_kernel<0, 1><<<dim3(12, 128), 256, 0, stream>>>(S0, Wm, bm, S2, NT, D_, D_, scores, pooled);
    // 10. merge + residual: h -> S3, prefill out = h
    merge_kernel<<<dim3(NT, 3), 256, 0, stream>>>(x, mask, S1, S2, S3, out);
    // 11. LN2: n2 -> S4
    ln_kernel<false><<<NT, 256, 0, stream>>>(S3, g2, b2, nullptr, nullptr, S4, nullptr);
    // 12. FFN in 4 chunks of 2048 tokens (mid reuses S0: 2048*3072 floats)
    for (int c = 0; c < 4; c++) {
        const float* n2c = S4 + (size_t)c * 2048 * D_;
        float* outc = out + (size_t)c * 2048 * D_;
        gemm_kernel<1, 0><<<dim3(48, 32), 256, 0, stream>>>(n2c, W1, bf1, S0, 2048, F_, D_, nullptr, nullptr);
        gemm_kernel<2, 0><<<dim3(12, 32), 256, 0, stream>>>(S0, W2, bf2, outc, 2048, D_, F_, nullptr, nullptr);
    }
}

// Round 2
// 754.898 us; speedup vs baseline: 6.3065x; 6.3065x over previous
//
#include <hip/hip_runtime.h>
#include <math.h>

#define B_ 4
#define L_ 2048
#define D_ 768
#define H_ 12
#define F_ 3072
#define KTOP 307
#define LN_EPS 1e-5f

typedef unsigned int u32;
typedef unsigned short u16;
using bf16x8 = __attribute__((ext_vector_type(8))) short;
using f32x4  = __attribute__((ext_vector_type(4))) float;

#define AS1 __attribute__((address_space(1)))
#define AS3 __attribute__((address_space(3)))

__device__ __forceinline__ void gl16(const void* g, void* l) {
    __builtin_amdgcn_global_load_lds((const AS1 u32*)g, (AS3 u32*)l, 16, 0, 0);
}
__device__ __forceinline__ u16 f2bf(float f) {
    u32 u = __float_as_uint(f);
    return (u16)((u + 0x7fff + ((u >> 16) & 1)) >> 16);
}
__device__ __forceinline__ float bf2f(u16 s) {
    return __uint_as_float(((u32)s) << 16);
}
__device__ __forceinline__ float gelu_exact(float v) {
    return 0.5f * v * (1.0f + erff(v * 0.70710678118654752f));
}

// ---------------- block reduce (256 threads) ----------------
__device__ __forceinline__ float blk_reduce_sum(float v, float* red) {
    #pragma unroll
    for (int off = 32; off; off >>= 1) v += __shfl_xor(v, off, 64);
    __syncthreads();
    if ((threadIdx.x & 63) == 0) red[threadIdx.x >> 6] = v;
    __syncthreads();
    return red[0] + red[1] + red[2] + red[3];
}

// ---------------- LN -> bf16 normed (+ optional fp32 router score) ----------------
template <bool SCORE>
__global__ __launch_bounds__(256) void ln_kernel(
    const float* __restrict__ x, const float* __restrict__ g,
    const float* __restrict__ be, const float* __restrict__ Wr,
    const float* __restrict__ brp, u16* __restrict__ outn,
    float* __restrict__ scores)
{
    __shared__ float red[4];
    const int t = blockIdx.x;
    const int tid = threadIdx.x;
    const float* xr = x + (size_t)t * D_;
    float v0 = xr[tid], v1 = xr[tid + 256], v2 = xr[tid + 512];
    float mean = blk_reduce_sum(v0 + v1 + v2, red) * (1.0f / 768.0f);
    float d0 = v0 - mean, d1 = v1 - mean, d2 = v2 - mean;
    __syncthreads();
    float var = blk_reduce_sum(d0 * d0 + d1 * d1 + d2 * d2, red) * (1.0f / 768.0f);
    float inv = 1.0f / sqrtf(var + LN_EPS);
    float n0 = d0 * inv * g[tid] + be[tid];
    float n1 = d1 * inv * g[tid + 256] + be[tid + 256];
    float n2 = d2 * inv * g[tid + 512] + be[tid + 512];
    u16* orow = outn + (size_t)t * D_;
    orow[tid] = f2bf(n0); orow[tid + 256] = f2bf(n1); orow[tid + 512] = f2bf(n2);
    if (SCORE) {
        __syncthreads();
        float dot = blk_reduce_sum(n0 * Wr[tid] + n1 * Wr[tid + 256] + n2 * Wr[tid + 512], red);
        if (tid == 0) scores[t] = 1.0f / (1.0f + expf(-(dot + brp[0])));
    }
}

// ---------------- top-k (lowest K scores) + score-sum ----------------
__global__ __launch_bounds__(256) void topk_kernel(
    const float* __restrict__ scores, unsigned* __restrict__ mask,
    float* __restrict__ ssum)
{
    __shared__ unsigned long long keys[L_];
    __shared__ float red[4];
    const int b = blockIdx.x, tid = threadIdx.x;
    float local = 0.f;
    for (int i = tid; i < L_; i += 256) {
        float sc = scores[b * L_ + i];
        keys[i] = ((unsigned long long)__float_as_uint(sc) << 32) | (unsigned)i;
        local += sc;
    }
    float tot = blk_reduce_sum(local, red);
    if (tid == 0) ssum[b] = tot;
    __syncthreads();
    for (int size = 2; size <= L_; size <<= 1) {
        for (int stride = size >> 1; stride > 0; stride >>= 1) {
            for (int i = tid; i < L_; i += 256) {
                int j = i ^ stride;
                if (j > i) {
                    bool up = ((i & size) == 0);
                    unsigned long long a = keys[i], c = keys[j];
                    if ((a > c) == up) { keys[i] = c; keys[j] = a; }
                }
            }
            __syncthreads();
        }
    }
    unsigned long long cutoff = keys[KTOP - 1];
    for (int i = tid; i < L_; i += 256) {
        float sc = scores[b * L_ + i];
        unsigned long long k = ((unsigned long long)__float_as_uint(sc) << 32) | (unsigned)i;
        mask[b * L_ + i] = (k <= cutoff) ? 1u : 0u;
    }
}

// ---------------- pooled partials: parts[lc][b][d] = sum_{l in chunk} s*normed ----------------
__global__ __launch_bounds__(256) void pooled_part(
    const float* __restrict__ scores, const u16* __restrict__ nb,
    float* __restrict__ parts)
{
    const int lc = blockIdx.x, b = blockIdx.y, tid = threadIdx.x;
    float a0 = 0.f, a1 = 0.f, a2 = 0.f;
    for (int l = lc * 256; l < lc * 256 + 256; l++) {
        float s = scores[b * L_ + l];
        const u16* row = nb + (size_t)(b * L_ + l) * D_;
        a0 += s * bf2f(row[tid]);
        a1 += s * bf2f(row[tid + 256]);
        a2 += s * bf2f(row[tid + 512]);
    }
    float* p = parts + (size_t)(lc * B_ + b) * D_;
    p[tid] = a0; p[tid + 256] = a1; p[tid + 512] = a2;
}

__global__ __launch_bounds__(256) void pooled_combine(
    const float* __restrict__ parts, const float* __restrict__ ssum,
    float* __restrict__ pooled)
{
    const int b = blockIdx.y;
    const int d = blockIdx.x * 256 + threadIdx.x;
    float s = 0.f;
    #pragma unroll
    for (int lc = 0; lc < 8; lc++) s += parts[(size_t)(lc * B_ + b) * D_ + d];
    pooled[b * D_ + d] = s / (ssum[b] + 1e-6f);
}

// pWm[b][n] = sum_k pooled[b][k] * Wm[k][n]
__global__ __launch_bounds__(256) void pooledWm_kernel(
    const float* __restrict__ pooled, const float* __restrict__ Wm,
    float* __restrict__ pWm)
{
    const int b = blockIdx.y;
    const int n = blockIdx.x * 256 + threadIdx.x;
    float acc = 0.f;
    for (int k = 0; k < D_; k++) acc += pooled[b * D_ + k] * Wm[(size_t)k * D_ + n];
    pWm[b * D_ + n] = acc;
}

// ---------------- weight convert+transpose: W[K][N] fp32 -> WT[N][K] bf16 ----------------
__global__ __launch_bounds__(256) void wconv(
    const float* __restrict__ Win, u16* __restrict__ WT, int K, int N)
{
    __shared__ float t[32][33];
    const int tid = threadIdx.x;
    const int tx = tid & 31, ty = tid >> 5;
    const int n0 = blockIdx.x * 32, k0 = blockIdx.y * 32;
    #pragma unroll
    for (int i = 0; i < 4; i++)
        t[ty + i * 8][tx] = Win[(size_t)(k0 + ty + i * 8) * N + n0 + tx];
    __syncthreads();
    #pragma unroll
    for (int i = 0; i < 4; i++)
        WT[(size_t)(n0 + ty + i * 8) * K + k0 + tx] = f2bf(t[tx][ty + i * 8]);
}

__global__ __launch_bounds__(256) void biascat(
    const float* __restrict__ bq, const float* __restrict__ bk,
    const float* __restrict__ bv, float* __restrict__ bcat)
{
    int i = blockIdx.x * 256 + threadIdx.x;
    float v = (i < 768) ? bq[i] : (i < 1536) ? bk[i - 768] : bv[i - 1536];
    bcat[i] = v;
}

// ---------------- bf16 MFMA GEMM: C = epi(A[M][K] @ WT[N][K]^T + bias) ----------------
// EPI: 0 fp32, 1 bf16, 2 gelu->bf16, 3 merge->h fp32, 4 +hres fp32
template <int EPI>
__global__ __launch_bounds__(256) void mfma_gemm(
    const u16* __restrict__ A, const u16* __restrict__ Bt,
    const float* __restrict__ bias, void* __restrict__ Cout,
    int M, int N, int K,
    const float* __restrict__ x, const unsigned* __restrict__ msk,
    const float* __restrict__ attn, const float* __restrict__ scores,
    const float* __restrict__ pWm, const float* __restrict__ hres)
{
    __shared__ u16 Asm[128 * 64];
    __shared__ u16 Bsm[128 * 64];
    const int tid = threadIdx.x;
    const int wave = tid >> 6, lane = tid & 63;
    const int m0 = blockIdx.y * 128, n0 = blockIdx.x * 128;
    const int wm = (wave >> 1) * 64, wn = (wave & 1) * 64;

    f32x4 acc[4][4];
    #pragma unroll
    for (int i = 0; i < 4; i++)
        #pragma unroll
        for (int j = 0; j < 4; j++) acc[i][j] = 0.f;

    const u16* ap[4]; const u16* bp[4];
    #pragma unroll
    for (int i = 0; i < 4; i++) {
        int s = wave * 256 + i * 64 + lane;
        int row = s >> 3;
        int kq = (s & 7) ^ (row & 7);   // logical k-chunk stored at position s&7
        ap[i] = A  + (size_t)(m0 + row) * K + kq * 8;
        bp[i] = Bt + (size_t)(n0 + row) * K + kq * 8;
    }

    for (int k0 = 0; k0 < K; k0 += 64) {
        #pragma unroll
        for (int i = 0; i < 4; i++) {
            gl16(ap[i], &Asm[(wave * 256 + i * 64) * 8]);
            gl16(bp[i], &Bsm[(wave * 256 + i * 64) * 8]);
            ap[i] += 64; bp[i] += 64;
        }
        __syncthreads();
        #pragma unroll
        for (int kk = 0; kk < 2; kk++) {
            bf16x8 af[4], bf[4];
            const int kq = kk * 4 + (lane >> 4);
            #pragma unroll
            for (int mi = 0; mi < 4; mi++) {
                int row = wm + mi * 16 + (lane & 15);
                af[mi] = *(const bf16x8*)&Asm[(row * 8 + (kq ^ (row & 7))) * 8];
            }
            #pragma unroll
            for (int ni = 0; ni < 4; ni++) {
                int row = wn + ni * 16 + (lane & 15);
                bf[ni] = *(const bf16x8*)&Bsm[(row * 8 + (kq ^ (row & 7))) * 8];
            }
            #pragma unroll
            for (int mi = 0; mi < 4; mi++)
                #pragma unroll
                for (int ni = 0; ni < 4; ni++)
                    acc[mi][ni] = __builtin_amdgcn_mfma_f32_16x16x32_bf16(
                        af[mi], bf[ni], acc[mi][ni], 0, 0, 0);
        }
        __syncthreads();
    }

    #pragma unroll
    for (int mi = 0; mi < 4; mi++) {
        #pragma unroll
        for (int ni = 0; ni < 4; ni++) {
            #pragma unroll
            for (int r = 0; r < 4; r++) {
                int row = m0 + wm + mi * 16 + (lane >> 4) * 4 + r;
                int col = n0 + wn + ni * 16 + (lane & 15);
                float v = acc[mi][ni][r] + bias[col];
                size_t off = (size_t)row * N + col;
                if (EPI == 0) ((float*)Cout)[off] = v;
                else if (EPI == 1) ((u16*)Cout)[off] = f2bf(v);
                else if (EPI == 2) ((u16*)Cout)[off] = f2bf(gelu_exact(v));
                else if (EPI == 3) {
                    float mix = v + scores[row] * pWm[(row >> 11) * D_ + col];
                    float sel = msk[row] ? attn[off] : mix;
                    ((float*)Cout)[off] = x[off] + sel;
                } else {
                    ((float*)Cout)[off] = v + hres[off];
                }
            }
        }
    }
}

// ---------------- V transpose: V[token][ld slice] -> VT[(b*H+h)*64+d][L] ----------------
__global__ __launch_bounds__(256) void vtrans(
    const u16* __restrict__ V, u16* __restrict__ VT, int ld)
{
    __shared__ u16 tl[64 * 72];
    const int tid = threadIdx.x;
    const int l0 = blockIdx.x * 64, h = blockIdx.y, b = blockIdx.z;
    const u16* src = V + h * 64;
    {
        int r = tid >> 3, ch = tid & 7;
        *(uint4*)&tl[r * 72 + ch * 8] =
            *(const uint4*)&src[(size_t)(b * L_ + l0 + r) * ld + ch * 8];
        int t2 = tid + 256; r = t2 >> 3; ch = t2 & 7;
        *(uint4*)&tl[r * 72 + ch * 8] =
            *(const uint4*)&src[(size_t)(b * L_ + l0 + r) * ld + ch * 8];
    }
    __syncthreads();
    int d = tid >> 2, lg = (tid & 3) * 16;
    u16* dst = VT + (size_t)((b * H_ + h) * 64 + d) * L_ + l0 + lg;
    union { u16 s[8]; uint4 v; } pk;
    #pragma unroll
    for (int j = 0; j < 8; j++) pk.s[j] = tl[(lg + j) * 72 + d];
    *(uint4*)dst = pk.v;
    #pragma unroll
    for (int j = 0; j < 8; j++) pk.s[j] = tl[(lg + 8 + j) * 72 + d];
    *(uint4*)(dst + 8) = pk.v;
}

// ---------------- bf16 MFMA flash attention ----------------
// grid (L/64, H, B), 256 thr. Wave w: q rows blockIdx.x*64 + w*16 .. +15
__global__ __launch_bounds__(256) void attn_mfma(
    const u16* __restrict__ Qg, const u16* __restrict__ Kg,
    const u16* __restrict__ VTg, u16* __restrict__ ctx, int ldqk)
{
    __shared__ u16 Qs[64 * 72];
    __shared__ u16 Ks[64 * 72];
    __shared__ u16 VTs[64 * 72];
    __shared__ u16 Ps[4 * 16 * 72];
    const int tid = threadIdx.x, wave = tid >> 6, lane = tid & 63;
    const int h = blockIdx.y, b = blockIdx.z;
    const int q0 = blockIdx.x * 64;

    {
        int r = tid >> 3, ch = tid & 7;
        *(uint4*)&Qs[r * 72 + ch * 8] =
            *(const uint4*)&Qg[(size_t)(b * L_ + q0 + r) * ldqk + h * 64 + ch * 8];
        int t2 = tid + 256; r = t2 >> 3; ch = t2 & 7;
        *(uint4*)&Qs[r * 72 + ch * 8] =
            *(const uint4*)&Qg[(size_t)(b * L_ + q0 + r) * ldqk + h * 64 + ch * 8];
    }
    __syncthreads();
    bf16x8 qf[2];
    {
        int row = wave * 16 + (lane & 15);
        int q = lane >> 4;
        qf[0] = *(const bf16x8*)&Qs[row * 72 + q * 8];
        qf[1] = *(const bf16x8*)&Qs[row * 72 + 32 + q * 8];
    }
    f32x4 accO[4]; float m_i[4], l_i[4];
    #pragma unroll
    for (int i = 0; i < 4; i++) { accO[i] = 0.f; m_i[i] = -1e30f; l_i[i] = 0.f; }

    const u16* kbase = Kg + (size_t)(b * L_) * ldqk + h * 64;
    const u16* vbase = VTg + (size_t)((b * H_ + h) * 64) * L_;

    for (int kt = 0; kt < L_; kt += 64) {
        {
            int r = tid >> 3, ch = tid & 7;
            *(uint4*)&Ks[r * 72 + ch * 8] =
                *(const uint4*)&kbase[(size_t)(kt + r) * ldqk + ch * 8];
            *(uint4*)&VTs[r * 72 + ch * 8] =
                *(const uint4*)&vbase[(size_t)r * L_ + kt + ch * 8];
            int t2 = tid + 256; int r2 = t2 >> 3, ch2 = t2 & 7;
            *(uint4*)&Ks[r2 * 72 + ch2 * 8] =
                *(const uint4*)&kbase[(size_t)(kt + r2) * ldqk + ch2 * 8];
            *(uint4*)&VTs[r2 * 72 + ch2 * 8] =
                *(const uint4*)&vbase[(size_t)r2 * L_ + kt + ch2 * 8];
        }
        __syncthreads();

        f32x4 accS[4];
        #pragma unroll
        for (int ni = 0; ni < 4; ni++) accS[ni] = 0.f;
        #pragma unroll
        for (int kk = 0; kk < 2; kk++) {
            #pragma unroll
            for (int ni = 0; ni < 4; ni++) {
                bf16x8 kf = *(const bf16x8*)&Ks[(ni * 16 + (lane & 15)) * 72 + kk * 32 + (lane >> 4) * 8];
                accS[ni] = __builtin_amdgcn_mfma_f32_16x16x32_bf16(qf[kk], kf, accS[ni], 0, 0, 0);
            }
        }
        #pragma unroll
        for (int ni = 0; ni < 4; ni++) accS[ni] *= 0.125f;  // 1/sqrt(64)

        float alpha[4];
        #pragma unroll
        for (int r = 0; r < 4; r++) {
            float mx = fmaxf(fmaxf(accS[0][r], accS[1][r]), fmaxf(accS[2][r], accS[3][r]));
            #pragma unroll
            for (int off = 1; off < 16; off <<= 1) mx = fmaxf(mx, __shfl_xor(mx, off, 64));
            float mn = fmaxf(m_i[r], mx);
            alpha[r] = __expf(m_i[r] - mn);
            m_i[r] = mn;
            float rs = 0.f;
            #pragma unroll
            for (int ni = 0; ni < 4; ni++) {
                float p = __expf(accS[ni][r] - mn);
                accS[ni][r] = p; rs += p;
            }
            #pragma unroll
            for (int off = 1; off < 16; off <<= 1) rs += __shfl_xor(rs, off, 64);
            l_i[r] = l_i[r] * alpha[r] + rs;
        }
        #pragma unroll
        for (int ni = 0; ni < 4; ni++) {
            #pragma unroll
            for (int r = 0; r < 4; r++) {
                Ps[(wave * 16 + (lane >> 4) * 4 + r) * 72 + ni * 16 + (lane & 15)] = f2bf(accS[ni][r]);
                accO[ni][r] *= alpha[r];
            }
        }
        #pragma unroll
        for (int kk = 0; kk < 2; kk++) {
            bf16x8 pf = *(const bf16x8*)&Ps[(wave * 16 + (lane & 15)) * 72 + kk * 32 + (lane >> 4) * 8];
            #pragma unroll
            for (int ni = 0; ni < 4; ni++) {
                bf16x8 vf = *(const bf16x8*)&VTs[(ni * 16 + (lane & 15)) * 72 + kk * 32 + (lane >> 4) * 8];
                accO[ni] = __builtin_amdgcn_mfma_f32_16x16x32_bf16(pf, vf, accO[ni], 0, 0, 0);
            }
        }
        __syncthreads();
    }

    float inv[4];
    #pragma unroll
    for (int r = 0; r < 4; r++) inv[r] = 1.0f / l_i[r];
    u16* cb = ctx + (size_t)(b * L_ + q0 + wave * 16) * D_ + h * 64;
    #pragma unroll
    for (int ni = 0; ni < 4; ni++)
        #pragma unroll
        for (int r = 0; r < 4; r++)
            cb[((lane >> 4) * 4 + r) * D_ + ni * 16 + (lane & 15)] = f2bf(accO[ni][r] * inv[r]);
}

// ---------------- launch ----------------
extern "C" void kernel_launch(void* const* d_in, const int* in_sizes, int n_in,
                              void* d_out, int out_size, void* d_ws, size_t ws_size,
                              hipStream_t stream)
{
    const float* x   = (const float*)d_in[0];
    const float* g1  = (const float*)d_in[1];
    const float* b1  = (const float*)d_in[2];
    const float* g2  = (const float*)d_in[3];
    const float* b2  = (const float*)d_in[4];
    const float* Wr  = (const float*)d_in[5];
    const float* br  = (const float*)d_in[6];
    const float* Wq  = (const float*)d_in[7];
    const float* bq  = (const float*)d_in[8];
    const float* Wk  = (const float*)d_in[9];
    const float* bk  = (const float*)d_in[10];
    const float* Wv  = (const float*)d_in[11];
    const float* bv  = (const float*)d_in[12];
    const float* Wo  = (const float*)d_in[13];
    const float* bo  = (const float*)d_in[14];
    const float* Wm  = (const float*)d_in[15];
    const float* bm  = (const float*)d_in[16];
    const float* W1  = (const float*)d_in[17];
    const float* bf1 = (const float*)d_in[18];
    const float* W2  = (const float*)d_in[19];
    const float* bf2 = (const float*)d_in[20];
    float* out = (float*)d_out;

    char* W = (char*)d_ws;
    u16* WqT = (u16*)(W + 0);
    u16* WkT = (u16*)(W + 1179648);
    u16* WvT = (u16*)(W + 2359296);
    u16* WoT = (u16*)(W + 3538944);
    u16* WmT = (u16*)(W + 4718592);
    u16* W1T = (u16*)(W + 5898240);
    u16* W2T = (u16*)(W + 10616832);
    float* scores  = (float*)(W + 15335424);
    unsigned* mask = (unsigned*)(W + 15368192);
    float* ssum    = (float*)(W + 15400960);
    float* pooled  = (float*)(W + 15401216);
    float* pWm     = (float*)(W + 15413504);
    float* parts   = (float*)(W + 15425792);
    float* bcat    = (float*)(W + 15524096);
    u16* nb   = (u16*)(W + 15728640);
    u16* Y    = (u16*)(W + 28311552);   // [8192][2304] q|k|v
    u16* VT   = (u16*)(W + 66060288);
    u16* ctx  = (u16*)(W + 78643200);
    float* attn = (float*)(W + 91226112);
    float* h    = (float*)(W + 28311552);   // overlays Y (dead by then)
    u16* n2b    = (u16*)(W + 53477376);     // overlays Y tail
    u16* mid    = (u16*)(W + 66060288);     // overlays VT/ctx/attn

    // weight prep
    wconv<<<dim3(24, 24), 256, 0, stream>>>(Wq, WqT, 768, 768);
    wconv<<<dim3(24, 24), 256, 0, stream>>>(Wk, WkT, 768, 768);
    wconv<<<dim3(24, 24), 256, 0, stream>>>(Wv, WvT, 768, 768);
    wconv<<<dim3(24, 24), 256, 0, stream>>>(Wo, WoT, 768, 768);
    wconv<<<dim3(24, 24), 256, 0, stream>>>(Wm, WmT, 768, 768);
    wconv<<<dim3(96, 24), 256, 0, stream>>>(W1, W1T, 768, 3072);
    wconv<<<dim3(24, 96), 256, 0, stream>>>(W2, W2T, 3072, 768);
    biascat<<<9, 256, 0, stream>>>(bq, bk, bv, bcat);

    const int NT = B_ * L_;
    // LN1 + scores, routing, pooling
    ln_kernel<true><<<NT, 256, 0, stream>>>(x, g1, b1, Wr, br, nb, scores);
    topk_kernel<<<B_, 256, 0, stream>>>(scores, mask, ssum);
    pooled_part<<<dim3(8, B_), 256, 0, stream>>>(scores, nb, parts);
    pooled_combine<<<dim3(3, B_), 256, 0, stream>>>(parts, ssum, pooled);
    pooledWm_kernel<<<dim3(3, B_), 256, 0, stream>>>(pooled, Wm, pWm);

    // fused QKV projection -> Y bf16 [8192][2304]
    mfma_gemm<1><<<dim3(18, 64), 256, 0, stream>>>(nb, WqT, bcat, Y, NT, 2304, 768,
        nullptr, nullptr, nullptr, nullptr, nullptr, nullptr);
    // V transpose -> VT
    vtrans<<<dim3(32, H_, B_), 256, 0, stream>>>(Y + 1536, VT, 2304);
    // attention -> ctx bf16
    attn_mfma<<<dim3(32, H_, B_), 256, 0, stream>>>(Y, Y + 768, VT, ctx, 2304);
    // attn_out = ctx @ Wo + bo (fp32)
    mfma_gemm<0><<<dim3(6, 64), 256, 0, stream>>>(ctx, WoT, bo, attn, NT, 768, 768,
        nullptr, nullptr, nullptr, nullptr, nullptr, nullptr);
    // h = x + where(mask, attn, normed@Wm + bm + s*pWm)
    mfma_gemm<3><<<dim3(6, 64), 256, 0, stream>>>(nb, WmT, bm, h, NT, 768, 768,
        x, mask, attn, scores, pWm, nullptr);
    // LN2 -> n2 bf16
    ln_kernel<false><<<NT, 256, 0, stream>>>(h, g2, b2, nullptr, nullptr, n2b, nullptr);
    // FFN
    mfma_gemm<2><<<dim3(24, 64), 256, 0, stream>>>(n2b, W1T, bf1, mid, NT, 3072, 768,
        nullptr, nullptr, nullptr, nullptr, nullptr, nullptr);
    mfma_gemm<4><<<dim3(6, 64), 256, 0, stream>>>(mid, W2T, bf2, out, NT, 768, 3072,
        nullptr, nullptr, nullptr, nullptr, nullptr, h);
}

// Round 3
// 590.610 us; speedup vs baseline: 8.0608x; 1.2782x over previous
//
#include <hip/hip_runtime.h>
#include <math.h>

#define B_ 4
#define L_ 2048
#define D_ 768
#define H_ 12
#define F_ 3072
#define KTOP 307
#define KPAD 320
#define LN_EPS 1e-5f

typedef unsigned int u32;
typedef unsigned short u16;
using bf16x8 = __attribute__((ext_vector_type(8))) short;
using f32x4  = __attribute__((ext_vector_type(4))) float;

#define AS1 __attribute__((address_space(1)))
#define AS3 __attribute__((address_space(3)))

__device__ __forceinline__ void gl16(const void* g, void* l) {
    __builtin_amdgcn_global_load_lds((const AS1 u32*)g, (AS3 u32*)l, 16, 0, 0);
}
__device__ __forceinline__ u16 f2bf(float f) {
    u32 u = __float_as_uint(f);
    return (u16)((u + 0x7fff + ((u >> 16) & 1)) >> 16);
}
__device__ __forceinline__ float bf2f(u16 s) {
    return __uint_as_float(((u32)s) << 16);
}
__device__ __forceinline__ float gelu_exact(float v) {
    return 0.5f * v * (1.0f + erff(v * 0.70710678118654752f));
}

// ---------------- block reduce (256 threads) ----------------
__device__ __forceinline__ float blk_reduce_sum(float v, float* red) {
    #pragma unroll
    for (int off = 32; off; off >>= 1) v += __shfl_xor(v, off, 64);
    __syncthreads();
    if ((threadIdx.x & 63) == 0) red[threadIdx.x >> 6] = v;
    __syncthreads();
    return red[0] + red[1] + red[2] + red[3];
}

// ---------------- LN -> bf16 normed (+ optional fp32 router score) ----------------
template <bool SCORE>
__global__ __launch_bounds__(256) void ln_kernel(
    const float* __restrict__ x, const float* __restrict__ g,
    const float* __restrict__ be, const float* __restrict__ Wr,
    const float* __restrict__ brp, u16* __restrict__ outn,
    float* __restrict__ scores)
{
    __shared__ float red[4];
    const int t = blockIdx.x;
    const int tid = threadIdx.x;
    const float* xr = x + (size_t)t * D_;
    float v0 = xr[tid], v1 = xr[tid + 256], v2 = xr[tid + 512];
    float mean = blk_reduce_sum(v0 + v1 + v2, red) * (1.0f / 768.0f);
    float d0 = v0 - mean, d1 = v1 - mean, d2 = v2 - mean;
    __syncthreads();
    float var = blk_reduce_sum(d0 * d0 + d1 * d1 + d2 * d2, red) * (1.0f / 768.0f);
    float inv = 1.0f / sqrtf(var + LN_EPS);
    float n0 = d0 * inv * g[tid] + be[tid];
    float n1 = d1 * inv * g[tid + 256] + be[tid + 256];
    float n2 = d2 * inv * g[tid + 512] + be[tid + 512];
    u16* orow = outn + (size_t)t * D_;
    orow[tid] = f2bf(n0); orow[tid + 256] = f2bf(n1); orow[tid + 512] = f2bf(n2);
    if (SCORE) {
        __syncthreads();
        float dot = blk_reduce_sum(n0 * Wr[tid] + n1 * Wr[tid + 256] + n2 * Wr[tid + 512], red);
        if (tid == 0) scores[t] = 1.0f / (1.0f + expf(-(dot + brp[0])));
    }
}

// ---------------- top-k + compaction maps + score-sum ----------------
__global__ __launch_bounds__(256) void topk_kernel(
    const float* __restrict__ scores, unsigned* __restrict__ mask,
    float* __restrict__ ssum, int* __restrict__ rowmap, int* __restrict__ inv)
{
    __shared__ unsigned long long keys[L_];
    __shared__ float red[4];
    const int b = blockIdx.x, tid = threadIdx.x;
    float local = 0.f;
    for (int i = tid; i < L_; i += 256) {
        float sc = scores[b * L_ + i];
        keys[i] = ((unsigned long long)__float_as_uint(sc) << 32) | (unsigned)i;
        local += sc;
    }
    float tot = blk_reduce_sum(local, red);
    if (tid == 0) ssum[b] = tot;
    __syncthreads();
    for (int size = 2; size <= L_; size <<= 1) {
        for (int stride = size >> 1; stride > 0; stride >>= 1) {
            for (int i = tid; i < L_; i += 256) {
                int j = i ^ stride;
                if (j > i) {
                    bool up = ((i & size) == 0);
                    unsigned long long a = keys[i], c = keys[j];
                    if ((a > c) == up) { keys[i] = c; keys[j] = a; }
                }
            }
            __syncthreads();
        }
    }
    unsigned long long cutoff = keys[KTOP - 1];
    for (int i = tid; i < L_; i += 256) {
        float sc = scores[b * L_ + i];
        unsigned long long k = ((unsigned long long)__float_as_uint(sc) << 32) | (unsigned)i;
        bool in = (k <= cutoff);
        mask[b * L_ + i] = in ? 1u : 0u;
        if (!in) inv[b * L_ + i] = 0;
    }
    for (int i = tid; i < KTOP; i += 256) {
        int tok = (int)(keys[i] & 0xffffffffULL);
        rowmap[b * KPAD + i] = b * L_ + tok;
        inv[b * L_ + tok] = b * KPAD + i;
    }
    if (tid < KPAD - KTOP)
        rowmap[b * KPAD + KTOP + tid] = b * L_ + (int)(keys[0] & 0xffffffffULL);
}

// ---------------- pooled partials ----------------
__global__ __launch_bounds__(256) void pooled_part(
    const float* __restrict__ scores, const u16* __restrict__ nb,
    float* __restrict__ parts)
{
    const int lc = blockIdx.x, b = blockIdx.y, tid = threadIdx.x;
    float a0 = 0.f, a1 = 0.f, a2 = 0.f;
    for (int l = lc * 256; l < lc * 256 + 256; l++) {
        float s = scores[b * L_ + l];
        const u16* row = nb + (size_t)(b * L_ + l) * D_;
        a0 += s * bf2f(row[tid]);
        a1 += s * bf2f(row[tid + 256]);
        a2 += s * bf2f(row[tid + 512]);
    }
    float* p = parts + (size_t)(lc * B_ + b) * D_;
    p[tid] = a0; p[tid + 256] = a1; p[tid + 512] = a2;
}

__global__ __launch_bounds__(256) void pooled_combine(
    const float* __restrict__ parts, const float* __restrict__ ssum,
    float* __restrict__ pooled)
{
    const int b = blockIdx.y;
    const int d = blockIdx.x * 256 + threadIdx.x;
    float s = 0.f;
    #pragma unroll
    for (int lc = 0; lc < 8; lc++) s += parts[(size_t)(lc * B_ + b) * D_ + d];
    pooled[b * D_ + d] = s / (ssum[b] + 1e-6f);
}

// pWm[b][n] = sum_k pooled[b][k] * Wm[k][n]
__global__ __launch_bounds__(256) void pooledWm_kernel(
    const float* __restrict__ pooled, const float* __restrict__ Wm,
    float* __restrict__ pWm)
{
    const int b = blockIdx.y;
    const int n = blockIdx.x * 256 + threadIdx.x;
    float acc = 0.f;
    for (int k = 0; k < D_; k++) acc += pooled[b * D_ + k] * Wm[(size_t)k * D_ + n];
    pWm[b * D_ + n] = acc;
}

// ---------------- fused weight convert+transpose (all 7 weights, 1 launch) ----------------
__global__ __launch_bounds__(256) void wconv_all(
    const float* __restrict__ Wq, const float* __restrict__ Wk,
    const float* __restrict__ Wv, const float* __restrict__ Wo,
    const float* __restrict__ Wm, const float* __restrict__ W1,
    const float* __restrict__ W2,
    u16* __restrict__ WqT, u16* __restrict__ WkvT, u16* __restrict__ WoT,
    u16* __restrict__ WmT, u16* __restrict__ W1T, u16* __restrict__ W2T)
{
    __shared__ float t[32][33];
    int id = blockIdx.x;
    const float* src; u16* dst; int K, N, local; float sc = 1.f;
    if (id < 576)       { src = Wq; dst = WqT; K = 768; N = 768; local = id; sc = 0.125f; }
    else if (id < 1152) { src = Wk; dst = WkvT;            K = 768; N = 768; local = id - 576; }
    else if (id < 1728) { src = Wv; dst = WkvT + 768 * 768; K = 768; N = 768; local = id - 1152; }
    else if (id < 2304) { src = Wo; dst = WoT; K = 768; N = 768; local = id - 1728; }
    else if (id < 2880) { src = Wm; dst = WmT; K = 768; N = 768; local = id - 2304; }
    else if (id < 5184) { src = W1; dst = W1T; K = 768; N = 3072; local = id - 2880; }
    else                { src = W2; dst = W2T; K = 3072; N = 768; local = id - 5184; }
    const int ntiles = N >> 5;
    const int n0 = (local % ntiles) * 32, k0 = (local / ntiles) * 32;
    const int tid = threadIdx.x, tx = tid & 31, ty = tid >> 5;
    #pragma unroll
    for (int i = 0; i < 4; i++)
        t[ty + i * 8][tx] = src[(size_t)(k0 + ty + i * 8) * N + n0 + tx];
    __syncthreads();
    #pragma unroll
    for (int i = 0; i < 4; i++)
        dst[(size_t)(n0 + ty + i * 8) * K + k0 + tx] = f2bf(t[tx][ty + i * 8] * sc);
}

__global__ __launch_bounds__(256) void biasprep(
    const float* __restrict__ bq, const float* __restrict__ bk,
    const float* __restrict__ bv, float* __restrict__ bqs,
    float* __restrict__ bkv)
{
    int i = blockIdx.x * 256 + threadIdx.x;
    if (i < 768) {
        bqs[i] = bq[i] * 0.125f;
        bkv[i] = bk[i];
        bkv[768 + i] = bv[i];
    }
}

// ---------------- bf16 MFMA GEMM: C = epi(A[M][K] @ WT[N][K]^T + bias) ----------------
// EPI: 0 fp32, 1 bf16, 2 gelu->bf16, 3 merge->h fp32, 4 +hres fp32
// RMAP: A row index comes from rowmap[] (gathered A)
template <int EPI, bool RMAP>
__global__ __launch_bounds__(256) void mfma_gemm(
    const u16* __restrict__ A, const u16* __restrict__ Bt,
    const float* __restrict__ bias, void* __restrict__ Cout,
    int M, int N, int K,
    const float* __restrict__ x, const unsigned* __restrict__ msk,
    const float* __restrict__ attn, const float* __restrict__ scores,
    const float* __restrict__ pWm, const float* __restrict__ hres,
    const int* __restrict__ rowmap, const int* __restrict__ invmap)
{
    __shared__ u16 Asm[128 * 64];
    __shared__ u16 Bsm[128 * 64];
    const int tid = threadIdx.x;
    const int wave = tid >> 6, lane = tid & 63;
    const int m0 = blockIdx.y * 128, n0 = blockIdx.x * 128;
    const int wm = (wave >> 1) * 64, wn = (wave & 1) * 64;

    f32x4 acc[4][4];
    #pragma unroll
    for (int i = 0; i < 4; i++)
        #pragma unroll
        for (int j = 0; j < 4; j++) acc[i][j] = 0.f;

    const u16* ap[4]; const u16* bp[4];
    #pragma unroll
    for (int i = 0; i < 4; i++) {
        int s = wave * 256 + i * 64 + lane;
        int row = s >> 3;
        int kq = (s & 7) ^ (row & 7);
        int arow = RMAP ? rowmap[m0 + row] : (m0 + row);
        ap[i] = A  + (size_t)arow * K + kq * 8;
        bp[i] = Bt + (size_t)(n0 + row) * K + kq * 8;
    }

    for (int k0 = 0; k0 < K; k0 += 64) {
        #pragma unroll
        for (int i = 0; i < 4; i++) {
            gl16(ap[i], &Asm[(wave * 256 + i * 64) * 8]);
            gl16(bp[i], &Bsm[(wave * 256 + i * 64) * 8]);
            ap[i] += 64; bp[i] += 64;
        }
        __syncthreads();
        #pragma unroll
        for (int kk = 0; kk < 2; kk++) {
            bf16x8 af[4], bf[4];
            const int kq = kk * 4 + (lane >> 4);
            #pragma unroll
            for (int mi = 0; mi < 4; mi++) {
                int row = wm + mi * 16 + (lane & 15);
                af[mi] = *(const bf16x8*)&Asm[(row * 8 + (kq ^ (row & 7))) * 8];
            }
            #pragma unroll
            for (int ni = 0; ni < 4; ni++) {
                int row = wn + ni * 16 + (lane & 15);
                bf[ni] = *(const bf16x8*)&Bsm[(row * 8 + (kq ^ (row & 7))) * 8];
            }
            #pragma unroll
            for (int mi = 0; mi < 4; mi++)
                #pragma unroll
                for (int ni = 0; ni < 4; ni++)
                    acc[mi][ni] = __builtin_amdgcn_mfma_f32_16x16x32_bf16(
                        af[mi], bf[ni], acc[mi][ni], 0, 0, 0);
        }
        __syncthreads();
    }

    #pragma unroll
    for (int mi = 0; mi < 4; mi++) {
        #pragma unroll
        for (int ni = 0; ni < 4; ni++) {
            #pragma unroll
            for (int r = 0; r < 4; r++) {
                int row = m0 + wm + mi * 16 + (lane >> 4) * 4 + r;
                int col = n0 + wn + ni * 16 + (lane & 15);
                float v = acc[mi][ni][r] + bias[col];
                size_t off = (size_t)row * N + col;
                if (EPI == 0) ((float*)Cout)[off] = v;
                else if (EPI == 1) ((u16*)Cout)[off] = f2bf(v);
                else if (EPI == 2) ((u16*)Cout)[off] = f2bf(gelu_exact(v));
                else if (EPI == 3) {
                    float mix = v + scores[row] * pWm[(row >> 11) * D_ + col];
                    float sel = msk[row] ? attn[(size_t)invmap[row] * D_ + col] : mix;
                    ((float*)Cout)[off] = x[off] + sel;
                } else {
                    ((float*)Cout)[off] = v + hres[off];
                }
            }
        }
    }
}

// ---------------- V transpose: V[token][ld slice] -> VT[(b*H+h)*64+d][L] ----------------
__global__ __launch_bounds__(256) void vtrans(
    const u16* __restrict__ V, u16* __restrict__ VT, int ld)
{
    __shared__ u16 tl[64 * 72];
    const int tid = threadIdx.x;
    const int l0 = blockIdx.x * 64, h = blockIdx.y, b = blockIdx.z;
    const u16* src = V + h * 64;
    {
        int r = tid >> 3, ch = tid & 7;
        *(uint4*)&tl[r * 72 + ch * 8] =
            *(const uint4*)&src[(size_t)(b * L_ + l0 + r) * ld + ch * 8];
        int t2 = tid + 256; r = t2 >> 3; ch = t2 & 7;
        *(uint4*)&tl[r * 72 + ch * 8] =
            *(const uint4*)&src[(size_t)(b * L_ + l0 + r) * ld + ch * 8];
    }
    __syncthreads();
    int d = tid >> 2, lg = (tid & 3) * 16;
    u16* dst = VT + (size_t)((b * H_ + h) * 64 + d) * L_ + l0 + lg;
    union { u16 s[8]; uint4 v; } pk;
    #pragma unroll
    for (int j = 0; j < 8; j++) pk.s[j] = tl[(lg + j) * 72 + d];
    *(uint4*)dst = pk.v;
    #pragma unroll
    for (int j = 0; j < 8; j++) pk.s[j] = tl[(lg + 8 + j) * 72 + d];
    *(uint4*)(dst + 8) = pk.v;
}

// ---------------- compacted-Q MFMA attention, fixed-shift softmax ----------------
// grid (KPAD/64, H, B), 256 thr. Wave w owns q rows q0 + w*16 .. +15.
// Q pre-scaled by 1/8 (folded into WqT). exp without max-subtract (logits ~ +-2).
__global__ __launch_bounds__(256) void attn2(
    const u16* __restrict__ qcomp, const u16* __restrict__ Kg,
    const u16* __restrict__ VTg, u16* __restrict__ ctxc)
{
    __shared__ u16 Qs[64 * 64];
    __shared__ u16 Ks[64 * 64];
    __shared__ u16 Vs[64 * 64];
    __shared__ u16 Ps[4 * 16 * 72];
    const int tid = threadIdx.x, wave = tid >> 6, lane = tid & 63;
    const int quad = lane >> 4, l15 = lane & 15;
    const int qb = blockIdx.x, h = blockIdx.y, b = blockIdx.z;
    const int q0 = qb * 64;

    // stage Q (swizzled, gl16)
    {
        int s0 = wave * 64 + lane;
        int r = s0 >> 3, c = (s0 & 7) ^ (r & 7);
        gl16(qcomp + (size_t)(b * KPAD + q0 + r) * D_ + h * 64 + c * 8,
             &Qs[(wave * 64) * 8]);
        int s1 = s0 + 256;
        int r1 = s1 >> 3, c1 = (s1 & 7) ^ (r1 & 7);
        gl16(qcomp + (size_t)(b * KPAD + q0 + r1) * D_ + h * 64 + c1 * 8,
             &Qs[(256 + wave * 64) * 8]);
    }
    const u16 *kp0, *kp1, *vp0, *vp1;
    {
        int s0 = wave * 64 + lane;
        int r = s0 >> 3, c = (s0 & 7) ^ (r & 7);
        kp0 = Kg + (size_t)(b * L_ + r) * 1536 + h * 64 + c * 8;
        vp0 = VTg + (size_t)((b * H_ + h) * 64 + r) * L_ + c * 8;
        int s1 = s0 + 256;
        int r1 = s1 >> 3, c1 = (s1 & 7) ^ (r1 & 7);
        kp1 = Kg + (size_t)(b * L_ + r1) * 1536 + h * 64 + c1 * 8;
        vp1 = VTg + (size_t)((b * H_ + h) * 64 + r1) * L_ + c1 * 8;
    }
    __syncthreads();
    bf16x8 qf0, qf1;
    {
        int row = wave * 16 + l15;
        qf0 = *(const bf16x8*)&Qs[(row * 8 + ((quad)     ^ (row & 7))) * 8];
        qf1 = *(const bf16x8*)&Qs[(row * 8 + ((4 + quad) ^ (row & 7))) * 8];
    }
    f32x4 accO[4]; float lp[4];
    #pragma unroll
    for (int i = 0; i < 4; i++) { accO[i] = 0.f; lp[i] = 0.f; }
    u16* Psw = Ps + wave * 16 * 72;

    for (int kt = 0; kt < L_; kt += 64) {
        gl16(kp0, &Ks[(wave * 64) * 8]);        kp0 += (size_t)64 * 1536;
        gl16(kp1, &Ks[(256 + wave * 64) * 8]);  kp1 += (size_t)64 * 1536;
        gl16(vp0, &Vs[(wave * 64) * 8]);        vp0 += 64;
        gl16(vp1, &Vs[(256 + wave * 64) * 8]);  vp1 += 64;
        __syncthreads();

        f32x4 accS[4];
        #pragma unroll
        for (int ni = 0; ni < 4; ni++) accS[ni] = 0.f;
        #pragma unroll
        for (int kk = 0; kk < 2; kk++) {
            const int kq = kk * 4 + quad;
            #pragma unroll
            for (int ni = 0; ni < 4; ni++) {
                int row = ni * 16 + l15;
                bf16x8 kf = *(const bf16x8*)&Ks[(row * 8 + (kq ^ (row & 7))) * 8];
                accS[ni] = __builtin_amdgcn_mfma_f32_16x16x32_bf16(
                    kk ? qf1 : qf0, kf, accS[ni], 0, 0, 0);
            }
        }
        // fixed-shift softmax: p = exp(s), accumulate l, stash P in LDS (bf16)
        #pragma unroll
        for (int ni = 0; ni < 4; ni++) {
            #pragma unroll
            for (int r = 0; r < 4; r++) {
                float p = __expf(accS[ni][r]);
                lp[r] += p;
                Psw[(quad * 4 + r) * 72 + ni * 16 + l15] = f2bf(p);
            }
        }
        #pragma unroll
        for (int kk = 0; kk < 2; kk++) {
            bf16x8 pf = *(const bf16x8*)&Psw[l15 * 72 + kk * 32 + quad * 8];
            const int kq = kk * 4 + quad;
            #pragma unroll
            for (int ni = 0; ni < 4; ni++) {
                int row = ni * 16 + l15;
                bf16x8 vf = *(const bf16x8*)&Vs[(row * 8 + (kq ^ (row & 7))) * 8];
                accO[ni] = __builtin_amdgcn_mfma_f32_16x16x32_bf16(pf, vf, accO[ni], 0, 0, 0);
            }
        }
        __syncthreads();
    }

    float invl[4];
    #pragma unroll
    for (int r = 0; r < 4; r++) {
        float s = lp[r];
        s += __shfl_xor(s, 1, 64); s += __shfl_xor(s, 2, 64);
        s += __shfl_xor(s, 4, 64); s += __shfl_xor(s, 8, 64);
        invl[r] = 1.0f / s;
    }
    #pragma unroll
    for (int ni = 0; ni < 4; ni++) {
        #pragma unroll
        for (int r = 0; r < 4; r++) {
            int ql = q0 + wave * 16 + quad * 4 + r;
            if (ql < KTOP)
                ctxc[(size_t)(b * KPAD + ql) * D_ + h * 64 + ni * 16 + l15] =
                    f2bf(accO[ni][r] * invl[r]);
        }
    }
}

// ---------------- launch ----------------
extern "C" void kernel_launch(void* const* d_in, const int* in_sizes, int n_in,
                              void* d_out, int out_size, void* d_ws, size_t ws_size,
                              hipStream_t stream)
{
    const float* x   = (const float*)d_in[0];
    const float* g1  = (const float*)d_in[1];
    const float* b1  = (const float*)d_in[2];
    const float* g2  = (const float*)d_in[3];
    const float* b2  = (const float*)d_in[4];
    const float* Wr  = (const float*)d_in[5];
    const float* br  = (const float*)d_in[6];
    const float* Wq  = (const float*)d_in[7];
    const float* bq  = (const float*)d_in[8];
    const float* Wk  = (const float*)d_in[9];
    const float* bk  = (const float*)d_in[10];
    const float* Wv  = (const float*)d_in[11];
    const float* bv  = (const float*)d_in[12];
    const float* Wo  = (const float*)d_in[13];
    const float* bo  = (const float*)d_in[14];
    const float* Wm  = (const float*)d_in[15];
    const float* bm  = (const float*)d_in[16];
    const float* W1  = (const float*)d_in[17];
    const float* bf1 = (const float*)d_in[18];
    const float* W2  = (const float*)d_in[19];
    const float* bf2 = (const float*)d_in[20];
    float* out = (float*)d_out;

    char* W = (char*)d_ws;
    u16* WqT  = (u16*)(W + 0);          // 1179648
    u16* WkvT = (u16*)(W + 1179648);    // 2359296
    u16* WoT  = (u16*)(W + 3538944);
    u16* WmT  = (u16*)(W + 4718592);
    u16* W1T  = (u16*)(W + 5898240);    // 4718592
    u16* W2T  = (u16*)(W + 10616832);   // 4718592
    float* scores  = (float*)(W + 15335424);
    unsigned* mask = (unsigned*)(W + 15368192);
    float* ssum    = (float*)(W + 15400960);
    float* pooled  = (float*)(W + 15401216);
    float* pWm     = (float*)(W + 15413504);
    float* parts   = (float*)(W + 15425792);
    float* bkv     = (float*)(W + 15524096);
    float* bqs     = (float*)(W + 15530240);
    int* rowmap    = (int*)(W + 15533312);   // 1280 ints
    int* invmap    = (int*)(W + 15538432);   // 8192 ints
    u16* nb    = (u16*)(W + 15728640);   // 12582912 ; n2b overlays later
    u16* Y     = (u16*)(W + 28311552);   // 25165824 [8192][1536] k|v ; h overlays
    u16* qcomp = (u16*)(W + 53477376);   // 1966080 [1280][768]
    u16* ctxc  = (u16*)(W + 55443456);   // 1966080
    float* attnc = (float*)(W + 57409536); // 3932160 [1280][768]
    u16* VT    = (u16*)(W + 61341696);   // 12582912
    float* h   = (float*)(W + 28311552); // overlays Y (dead after attention)
    u16* n2b   = (u16*)(W + 15728640);   // overlays nb (dead after Wm gemm)
    u16* mid   = (u16*)(W + 53477376);   // 50331648, overlays qcomp..VT (all dead)

    // weight prep (single launch) + biases
    wconv_all<<<7488, 256, 0, stream>>>(Wq, Wk, Wv, Wo, Wm, W1, W2,
                                        WqT, WkvT, WoT, WmT, W1T, W2T);
    biasprep<<<3, 256, 0, stream>>>(bq, bk, bv, bqs, bkv);

    const int NT = B_ * L_;
    // LN1 + scores, routing, pooling
    ln_kernel<true><<<NT, 256, 0, stream>>>(x, g1, b1, Wr, br, nb, scores);
    topk_kernel<<<B_, 256, 0, stream>>>(scores, mask, ssum, rowmap, invmap);
    pooled_part<<<dim3(8, B_), 256, 0, stream>>>(scores, nb, parts);
    pooled_combine<<<dim3(3, B_), 256, 0, stream>>>(parts, ssum, pooled);
    pooledWm_kernel<<<dim3(3, B_), 256, 0, stream>>>(pooled, Wm, pWm);

    // dense KV projection -> Y [8192][1536]
    mfma_gemm<1, false><<<dim3(12, 64), 256, 0, stream>>>(nb, WkvT, bkv, Y, NT, 1536, 768,
        nullptr, nullptr, nullptr, nullptr, nullptr, nullptr, nullptr, nullptr);
    // gathered Q projection (scaled 1/8) -> qcomp [1280][768]
    mfma_gemm<1, true><<<dim3(6, 10), 256, 0, stream>>>(nb, WqT, bqs, qcomp, KPAD * B_, 768, 768,
        nullptr, nullptr, nullptr, nullptr, nullptr, nullptr, rowmap, nullptr);
    // V transpose -> VT
    vtrans<<<dim3(32, H_, B_), 256, 0, stream>>>(Y + 768, VT, 1536);
    // compacted attention -> ctxc
    attn2<<<dim3(KPAD / 64, H_, B_), 256, 0, stream>>>(qcomp, Y, VT, ctxc);
    // attn_out (compact) = ctxc @ Wo + bo
    mfma_gemm<0, false><<<dim3(6, 10), 256, 0, stream>>>(ctxc, WoT, bo, attnc, KPAD * B_, 768, 768,
        nullptr, nullptr, nullptr, nullptr, nullptr, nullptr, nullptr, nullptr);
    // h = x + where(mask, attnc[inv], normed@Wm + bm + s*pWm)
    mfma_gemm<3, false><<<dim3(6, 64), 256, 0, stream>>>(nb, WmT, bm, h, NT, 768, 768,
        x, mask, attnc, scores, pWm, nullptr, nullptr, invmap);
    // LN2 -> n2b (overlays nb)
    ln_kernel<false><<<NT, 256, 0, stream>>>(h, g2, b2, nullptr, nullptr, n2b, nullptr);
    // FFN
    mfma_gemm<2, false><<<dim3(24, 64), 256, 0, stream>>>(n2b, W1T, bf1, mid, NT, 3072, 768,
        nullptr, nullptr, nullptr, nullptr, nullptr, nullptr, nullptr, nullptr);
    mfma_gemm<4, false><<<dim3(6, 64), 256, 0, stream>>>(mid, W2T, bf2, out, NT, 768, 3072,
        nullptr, nullptr, nullptr, nullptr, nullptr, h, nullptr, nullptr);
}

// Round 5
// 536.007 us; speedup vs baseline: 8.8819x; 1.1019x over previous
//
#include <hip/hip_runtime.h>
#include <math.h>

#define B_ 4
#define L_ 2048
#define D_ 768
#define H_ 12
#define F_ 3072
#define KTOP 307
#define KPAD 320
#define LN_EPS 1e-5f

typedef unsigned int u32;
typedef unsigned short u16;
using bf16x8 = __attribute__((ext_vector_type(8))) short;
using f32x4  = __attribute__((ext_vector_type(4))) float;

#define AS1 __attribute__((address_space(1)))
#define AS3 __attribute__((address_space(3)))

__device__ __forceinline__ void gl16(const void* g, void* l) {
    __builtin_amdgcn_global_load_lds((const AS1 u32*)g, (AS3 u32*)l, 16, 0, 0);
}
// explicit drain of the global_load_lds queue; do NOT trust compiler analysis here
__device__ __forceinline__ void wait_vm0() {
    asm volatile("s_waitcnt vmcnt(0)" ::: "memory");
}
__device__ __forceinline__ u16 f2bf(float f) {
    u32 u = __float_as_uint(f);
    return (u16)((u + 0x7fff + ((u >> 16) & 1)) >> 16);
}
__device__ __forceinline__ float bf2f(u16 s) {
    return __uint_as_float(((u32)s) << 16);
}
__device__ __forceinline__ float gelu_exact(float v) {
    return 0.5f * v * (1.0f + erff(v * 0.70710678118654752f));
}

// ---------------- block reduce (256 threads) ----------------
__device__ __forceinline__ float blk_reduce_sum(float v, float* red) {
    #pragma unroll
    for (int off = 32; off; off >>= 1) v += __shfl_xor(v, off, 64);
    __syncthreads();
    if ((threadIdx.x & 63) == 0) red[threadIdx.x >> 6] = v;
    __syncthreads();
    return red[0] + red[1] + red[2] + red[3];
}

// ---------------- LN -> bf16 normed (+ optional fp32 router score) ----------------
template <bool SCORE>
__global__ __launch_bounds__(256) void ln_kernel(
    const float* __restrict__ x, const float* __restrict__ g,
    const float* __restrict__ be, const float* __restrict__ Wr,
    const float* __restrict__ brp, u16* __restrict__ outn,
    float* __restrict__ scores)
{
    __shared__ float red[4];
    const int t = blockIdx.x;
    const int tid = threadIdx.x;
    const float* xr = x + (size_t)t * D_;
    float v0 = xr[tid], v1 = xr[tid + 256], v2 = xr[tid + 512];
    float mean = blk_reduce_sum(v0 + v1 + v2, red) * (1.0f / 768.0f);
    float d0 = v0 - mean, d1 = v1 - mean, d2 = v2 - mean;
    __syncthreads();
    float var = blk_reduce_sum(d0 * d0 + d1 * d1 + d2 * d2, red) * (1.0f / 768.0f);
    float inv = 1.0f / sqrtf(var + LN_EPS);
    float n0 = d0 * inv * g[tid] + be[tid];
    float n1 = d1 * inv * g[tid + 256] + be[tid + 256];
    float n2 = d2 * inv * g[tid + 512] + be[tid + 512];
    u16* orow = outn + (size_t)t * D_;
    orow[tid] = f2bf(n0); orow[tid + 256] = f2bf(n1); orow[tid + 512] = f2bf(n2);
    if (SCORE) {
        __syncthreads();
        float dot = blk_reduce_sum(n0 * Wr[tid] + n1 * Wr[tid + 256] + n2 * Wr[tid + 512], red);
        if (tid == 0) scores[t] = 1.0f / (1.0f + expf(-(dot + brp[0])));
    }
}

// ---------------- top-k + compaction maps + score-sum ----------------
__global__ __launch_bounds__(256) void topk_kernel(
    const float* __restrict__ scores, unsigned* __restrict__ mask,
    float* __restrict__ ssum, int* __restrict__ rowmap, int* __restrict__ inv)
{
    __shared__ unsigned long long keys[L_];
    __shared__ float red[4];
    const int b = blockIdx.x, tid = threadIdx.x;
    float local = 0.f;
    for (int i = tid; i < L_; i += 256) {
        float sc = scores[b * L_ + i];
        keys[i] = ((unsigned long long)__float_as_uint(sc) << 32) | (unsigned)i;
        local += sc;
    }
    float tot = blk_reduce_sum(local, red);
    if (tid == 0) ssum[b] = tot;
    __syncthreads();
    for (int size = 2; size <= L_; size <<= 1) {
        for (int stride = size >> 1; stride > 0; stride >>= 1) {
            for (int i = tid; i < L_; i += 256) {
                int j = i ^ stride;
                if (j > i) {
                    bool up = ((i & size) == 0);
                    unsigned long long a = keys[i], c = keys[j];
                    if ((a > c) == up) { keys[i] = c; keys[j] = a; }
                }
            }
            __syncthreads();
        }
    }
    unsigned long long cutoff = keys[KTOP - 1];
    for (int i = tid; i < L_; i += 256) {
        float sc = scores[b * L_ + i];
        unsigned long long k = ((unsigned long long)__float_as_uint(sc) << 32) | (unsigned)i;
        bool in = (k <= cutoff);
        mask[b * L_ + i] = in ? 1u : 0u;
        if (!in) inv[b * L_ + i] = 0;
    }
    for (int i = tid; i < KTOP; i += 256) {
        int tok = (int)(keys[i] & 0xffffffffULL);
        rowmap[b * KPAD + i] = b * L_ + tok;
        inv[b * L_ + tok] = b * KPAD + i;
    }
    if (tid < KPAD - KTOP)
        rowmap[b * KPAD + KTOP + tid] = b * L_ + (int)(keys[0] & 0xffffffffULL);
}

// ---------------- pooled partials ----------------
__global__ __launch_bounds__(256) void pooled_part(
    const float* __restrict__ scores, const u16* __restrict__ nb,
    float* __restrict__ parts)
{
    const int lc = blockIdx.x, b = blockIdx.y, tid = threadIdx.x;
    float a0 = 0.f, a1 = 0.f, a2 = 0.f;
    for (int l = lc * 256; l < lc * 256 + 256; l++) {
        float s = scores[b * L_ + l];
        const u16* row = nb + (size_t)(b * L_ + l) * D_;
        a0 += s * bf2f(row[tid]);
        a1 += s * bf2f(row[tid + 256]);
        a2 += s * bf2f(row[tid + 512]);
    }
    float* p = parts + (size_t)(lc * B_ + b) * D_;
    p[tid] = a0; p[tid + 256] = a1; p[tid + 512] = a2;
}

__global__ __launch_bounds__(256) void pooled_combine(
    const float* __restrict__ parts, const float* __restrict__ ssum,
    float* __restrict__ pooled)
{
    const int b = blockIdx.y;
    const int d = blockIdx.x * 256 + threadIdx.x;
    float s = 0.f;
    #pragma unroll
    for (int lc = 0; lc < 8; lc++) s += parts[(size_t)(lc * B_ + b) * D_ + d];
    pooled[b * D_ + d] = s / (ssum[b] + 1e-6f);
}

// pWm[b][n] = sum_k pooled[b][k] * Wm[k][n]
__global__ __launch_bounds__(256) void pooledWm_kernel(
    const float* __restrict__ pooled, const float* __restrict__ Wm,
    float* __restrict__ pWm)
{
    const int b = blockIdx.y;
    const int n = blockIdx.x * 256 + threadIdx.x;
    float acc = 0.f;
    for (int k = 0; k < D_; k++) acc += pooled[b * D_ + k] * Wm[(size_t)k * D_ + n];
    pWm[b * D_ + n] = acc;
}

// ---------------- fused weight convert+transpose (all 7 weights, 1 launch) ----------------
__global__ __launch_bounds__(256) void wconv_all(
    const float* __restrict__ Wq, const float* __restrict__ Wk,
    const float* __restrict__ Wv, const float* __restrict__ Wo,
    const float* __restrict__ Wm, const float* __restrict__ W1,
    const float* __restrict__ W2,
    u16* __restrict__ WqT, u16* __restrict__ WkvT, u16* __restrict__ WoT,
    u16* __restrict__ WmT, u16* __restrict__ W1T, u16* __restrict__ W2T)
{
    __shared__ float t[32][33];
    int id = blockIdx.x;
    const float* src; u16* dst; int K, N, local; float sc = 1.f;
    if (id < 576)       { src = Wq; dst = WqT; K = 768; N = 768; local = id; sc = 0.125f; }
    else if (id < 1152) { src = Wk; dst = WkvT;            K = 768; N = 768; local = id - 576; }
    else if (id < 1728) { src = Wv; dst = WkvT + 768 * 768; K = 768; N = 768; local = id - 1152; }
    else if (id < 2304) { src = Wo; dst = WoT; K = 768; N = 768; local = id - 1728; }
    else if (id < 2880) { src = Wm; dst = WmT; K = 768; N = 768; local = id - 2304; }
    else if (id < 5184) { src = W1; dst = W1T; K = 768; N = 3072; local = id - 2880; }
    else                { src = W2; dst = W2T; K = 3072; N = 768; local = id - 5184; }
    const int ntiles = N >> 5;
    const int n0 = (local % ntiles) * 32, k0 = (local / ntiles) * 32;
    const int tid = threadIdx.x, tx = tid & 31, ty = tid >> 5;
    #pragma unroll
    for (int i = 0; i < 4; i++)
        t[ty + i * 8][tx] = src[(size_t)(k0 + ty + i * 8) * N + n0 + tx];
    __syncthreads();
    #pragma unroll
    for (int i = 0; i < 4; i++)
        dst[(size_t)(n0 + ty + i * 8) * K + k0 + tx] = f2bf(t[tx][ty + i * 8] * sc);
}

__global__ __launch_bounds__(256) void biasprep(
    const float* __restrict__ bq, const float* __restrict__ bk,
    const float* __restrict__ bv, float* __restrict__ bqs,
    float* __restrict__ bkv)
{
    int i = blockIdx.x * 256 + threadIdx.x;
    if (i < 768) {
        bqs[i] = bq[i] * 0.125f;
        bkv[i] = bk[i];
        bkv[768 + i] = bv[i];
    }
}

// ---------------- bf16 MFMA GEMM: C = epi(A[M][K] @ WT[N][K]^T + bias) ----------------
// EPI: 0 fp32, 1 bf16, 2 gelu->bf16, 3 merge->h fp32, 4 +hres fp32
// RMAP: A row gathered through rowmap[]
// TM: 128 (4 waves 2x2, 64x64 each) or 64 (4 waves 1x4, 64x32 each); TN fixed 128.
// 1D grid, IDENTITY ordering (n-fastest). No swizzle this round (bisection).
template <int EPI, bool RMAP, int TM>
__global__ __launch_bounds__(256) void mfma_gemm(
    const u16* __restrict__ A, const u16* __restrict__ Bt,
    const float* __restrict__ bias, void* __restrict__ Cout,
    int N, int K, int nbn,
    const float* __restrict__ x, const unsigned* __restrict__ msk,
    const float* __restrict__ attn, const float* __restrict__ scores,
    const float* __restrict__ pWm, const float* __restrict__ hres,
    const int* __restrict__ rowmap, const int* __restrict__ invmap)
{
    constexpr int NI = (TM == 128) ? 4 : 2;
    constexpr int ASLOTS = TM * 8 / 256;   // gl16 slots per thread for A
    __shared__ u16 Asm[TM * 64];
    __shared__ u16 Bsm[128 * 64];
    const int tid = threadIdx.x;
    const int wave = tid >> 6, lane = tid & 63;
    const int quad = lane >> 4, l15 = lane & 15;

    const int wid = blockIdx.x;   // identity mapping (bisect: no XCD swizzle)
    const int m0 = (wid / nbn) * TM, n0 = (wid % nbn) * 128;
    const int wm = (TM == 128) ? (wave >> 1) * 64 : 0;
    const int wn = (TM == 128) ? (wave & 1) * 64 : wave * 32;

    f32x4 acc[4][NI];
    #pragma unroll
    for (int i = 0; i < 4; i++)
        #pragma unroll
        for (int j = 0; j < NI; j++) acc[i][j] = 0.f;

    const u16* ap[ASLOTS]; const u16* bp[4];
    #pragma unroll
    for (int i = 0; i < ASLOTS; i++) {
        int s = i * 256 + tid;
        int row = s >> 3;
        int kq = (s & 7) ^ (row & 7);
        int arow = RMAP ? rowmap[m0 + row] : (m0 + row);
        ap[i] = A + (size_t)arow * K + kq * 8;
    }
    #pragma unroll
    for (int i = 0; i < 4; i++) {
        int s = i * 256 + tid;
        int row = s >> 3;
        int kq = (s & 7) ^ (row & 7);
        bp[i] = Bt + (size_t)(n0 + row) * K + kq * 8;
    }

    for (int k0 = 0; k0 < K; k0 += 64) {
        #pragma unroll
        for (int i = 0; i < ASLOTS; i++) {
            gl16(ap[i], &Asm[(i * 256 + wave * 64) * 8]);
            ap[i] += 64;
        }
        #pragma unroll
        for (int i = 0; i < 4; i++) {
            gl16(bp[i], &Bsm[(i * 256 + wave * 64) * 8]);
            bp[i] += 64;
        }
        wait_vm0();          // explicit LDS-DMA drain before barrier
        __syncthreads();
        #pragma unroll
        for (int kk = 0; kk < 2; kk++) {
            bf16x8 af[4], bf[NI];
            const int kq = kk * 4 + quad;
            #pragma unroll
            for (int mi = 0; mi < 4; mi++) {
                int row = wm + mi * 16 + l15;
                af[mi] = *(const bf16x8*)&Asm[(row * 8 + (kq ^ (row & 7))) * 8];
            }
            #pragma unroll
            for (int ni = 0; ni < NI; ni++) {
                int row = wn + ni * 16 + l15;
                bf[ni] = *(const bf16x8*)&Bsm[(row * 8 + (kq ^ (row & 7))) * 8];
            }
            #pragma unroll
            for (int mi = 0; mi < 4; mi++)
                #pragma unroll
                for (int ni = 0; ni < NI; ni++)
                    acc[mi][ni] = __builtin_amdgcn_mfma_f32_16x16x32_bf16(
                        af[mi], bf[ni], acc[mi][ni], 0, 0, 0);
        }
        __syncthreads();
    }

    #pragma unroll
    for (int mi = 0; mi < 4; mi++) {
        #pragma unroll
        for (int ni = 0; ni < NI; ni++) {
            #pragma unroll
            for (int r = 0; r < 4; r++) {
                int row = m0 + wm + mi * 16 + quad * 4 + r;
                int col = n0 + wn + ni * 16 + l15;
                float v = acc[mi][ni][r] + bias[col];
                size_t off = (size_t)row * N + col;
                if (EPI == 0) ((float*)Cout)[off] = v;
                else if (EPI == 1) ((u16*)Cout)[off] = f2bf(v);
                else if (EPI == 2) ((u16*)Cout)[off] = f2bf(gelu_exact(v));
                else if (EPI == 3) {
                    float mix = v + scores[row] * pWm[(row >> 11) * D_ + col];
                    float sel = msk[row] ? attn[(size_t)invmap[row] * D_ + col] : mix;
                    ((float*)Cout)[off] = x[off] + sel;
                } else {
                    ((float*)Cout)[off] = v + hres[off];
                }
            }
        }
    }
}

// ---------------- V transpose: V[token][ld slice] -> VT[(b*H+h)*64+d][L] ----------------
__global__ __launch_bounds__(256) void vtrans(
    const u16* __restrict__ V, u16* __restrict__ VT, int ld)
{
    __shared__ u16 tl[64 * 72];
    const int tid = threadIdx.x;
    const int l0 = blockIdx.x * 64, h = blockIdx.y, b = blockIdx.z;
    const u16* src = V + h * 64;
    {
        int r = tid >> 3, ch = tid & 7;
        *(uint4*)&tl[r * 72 + ch * 8] =
            *(const uint4*)&src[(size_t)(b * L_ + l0 + r) * ld + ch * 8];
        int t2 = tid + 256; r = t2 >> 3; ch = t2 & 7;
        *(uint4*)&tl[r * 72 + ch * 8] =
            *(const uint4*)&src[(size_t)(b * L_ + l0 + r) * ld + ch * 8];
    }
    __syncthreads();
    int d = tid >> 2, lg = (tid & 3) * 16;
    u16* dst = VT + (size_t)((b * H_ + h) * 64 + d) * L_ + l0 + lg;
    union { u16 s[8]; uint4 v; } pk;
    #pragma unroll
    for (int j = 0; j < 8; j++) pk.s[j] = tl[(lg + j) * 72 + d];
    *(uint4*)dst = pk.v;
    #pragma unroll
    for (int j = 0; j < 8; j++) pk.s[j] = tl[(lg + 8 + j) * 72 + d];
    *(uint4*)(dst + 8) = pk.v;
}

// ---------------- compacted-Q MFMA attention, fixed-shift softmax ----------------
__global__ __launch_bounds__(256) void attn2(
    const u16* __restrict__ qcomp, const u16* __restrict__ Kg,
    const u16* __restrict__ VTg, u16* __restrict__ ctxc)
{
    __shared__ u16 Qs[64 * 64];
    __shared__ u16 Ks[64 * 64];
    __shared__ u16 Vs[64 * 64];
    __shared__ u16 Ps[4 * 16 * 72];
    const int tid = threadIdx.x, wave = tid >> 6, lane = tid & 63;
    const int quad = lane >> 4, l15 = lane & 15;
    const int qb = blockIdx.x, h = blockIdx.y, b = blockIdx.z;
    const int q0 = qb * 64;

    {
        int s0 = wave * 64 + lane;
        int r = s0 >> 3, c = (s0 & 7) ^ (r & 7);
        gl16(qcomp + (size_t)(b * KPAD + q0 + r) * D_ + h * 64 + c * 8,
             &Qs[(wave * 64) * 8]);
        int s1 = s0 + 256;
        int r1 = s1 >> 3, c1 = (s1 & 7) ^ (r1 & 7);
        gl16(qcomp + (size_t)(b * KPAD + q0 + r1) * D_ + h * 64 + c1 * 8,
             &Qs[(256 + wave * 64) * 8]);
    }
    const u16 *kp0, *kp1, *vp0, *vp1;
    {
        int s0 = wave * 64 + lane;
        int r = s0 >> 3, c = (s0 & 7) ^ (r & 7);
        kp0 = Kg + (size_t)(b * L_ + r) * 1536 + h * 64 + c * 8;
        vp0 = VTg + (size_t)((b * H_ + h) * 64 + r) * L_ + c * 8;
        int s1 = s0 + 256;
        int r1 = s1 >> 3, c1 = (s1 & 7) ^ (r1 & 7);
        kp1 = Kg + (size_t)(b * L_ + r1) * 1536 + h * 64 + c1 * 8;
        vp1 = VTg + (size_t)((b * H_ + h) * 64 + r1) * L_ + c1 * 8;
    }
    wait_vm0();
    __syncthreads();
    bf16x8 qf0, qf1;
    {
        int row = wave * 16 + l15;
        qf0 = *(const bf16x8*)&Qs[(row * 8 + ((quad)     ^ (row & 7))) * 8];
        qf1 = *(const bf16x8*)&Qs[(row * 8 + ((4 + quad) ^ (row & 7))) * 8];
    }
    f32x4 accO[4]; float lp[4];
    #pragma unroll
    for (int i = 0; i < 4; i++) { accO[i] = 0.f; lp[i] = 0.f; }
    u16* Psw = Ps + wave * 16 * 72;

    for (int kt = 0; kt < L_; kt += 64) {
        gl16(kp0, &Ks[(wave * 64) * 8]);        kp0 += (size_t)64 * 1536;
        gl16(kp1, &Ks[(256 + wave * 64) * 8]);  kp1 += (size_t)64 * 1536;
        gl16(vp0, &Vs[(wave * 64) * 8]);        vp0 += 64;
        gl16(vp1, &Vs[(256 + wave * 64) * 8]);  vp1 += 64;
        wait_vm0();
        __syncthreads();

        f32x4 accS[4];
        #pragma unroll
        for (int ni = 0; ni < 4; ni++) accS[ni] = 0.f;
        #pragma unroll
        for (int kk = 0; kk < 2; kk++) {
            const int kq = kk * 4 + quad;
            #pragma unroll
            for (int ni = 0; ni < 4; ni++) {
                int row = ni * 16 + l15;
                bf16x8 kf = *(const bf16x8*)&Ks[(row * 8 + (kq ^ (row & 7))) * 8];
                accS[ni] = __builtin_amdgcn_mfma_f32_16x16x32_bf16(
                    kk ? qf1 : qf0, kf, accS[ni], 0, 0, 0);
            }
        }
        #pragma unroll
        for (int ni = 0; ni < 4; ni++) {
            #pragma unroll
            for (int r = 0; r < 4; r++) {
                float p = __expf(accS[ni][r]);
                lp[r] += p;
                Psw[(quad * 4 + r) * 72 + ni * 16 + l15] = f2bf(p);
            }
        }
        #pragma unroll
        for (int kk = 0; kk < 2; kk++) {
            bf16x8 pf = *(const bf16x8*)&Psw[l15 * 72 + kk * 32 + quad * 8];
            const int kq = kk * 4 + quad;
            #pragma unroll
            for (int ni = 0; ni < 4; ni++) {
                int row = ni * 16 + l15;
                bf16x8 vf = *(const bf16x8*)&Vs[(row * 8 + (kq ^ (row & 7))) * 8];
                accO[ni] = __builtin_amdgcn_mfma_f32_16x16x32_bf16(pf, vf, accO[ni], 0, 0, 0);
            }
        }
        __syncthreads();
    }

    float invl[4];
    #pragma unroll
    for (int r = 0; r < 4; r++) {
        float s = lp[r];
        s += __shfl_xor(s, 1, 64); s += __shfl_xor(s, 2, 64);
        s += __shfl_xor(s, 4, 64); s += __shfl_xor(s, 8, 64);
        invl[r] = 1.0f / s;
    }
    #pragma unroll
    for (int ni = 0; ni < 4; ni++) {
        #pragma unroll
        for (int r = 0; r < 4; r++) {
            int ql = q0 + wave * 16 + quad * 4 + r;
            if (ql < KTOP)
                ctxc[(size_t)(b * KPAD + ql) * D_ + h * 64 + ni * 16 + l15] =
                    f2bf(accO[ni][r] * invl[r]);
        }
    }
}

// ---------------- launch ----------------
extern "C" void kernel_launch(void* const* d_in, const int* in_sizes, int n_in,
                              void* d_out, int out_size, void* d_ws, size_t ws_size,
                              hipStream_t stream)
{
    const float* x   = (const float*)d_in[0];
    const float* g1  = (const float*)d_in[1];
    const float* b1  = (const float*)d_in[2];
    const float* g2  = (const float*)d_in[3];
    const float* b2  = (const float*)d_in[4];
    const float* Wr  = (const float*)d_in[5];
    const float* br  = (const float*)d_in[6];
    const float* Wq  = (const float*)d_in[7];
    const float* bq  = (const float*)d_in[8];
    const float* Wk  = (const float*)d_in[9];
    const float* bk  = (const float*)d_in[10];
    const float* Wv  = (const float*)d_in[11];
    const float* bv  = (const float*)d_in[12];
    const float* Wo  = (const float*)d_in[13];
    const float* bo  = (const float*)d_in[14];
    const float* Wm  = (const float*)d_in[15];
    const float* bm  = (const float*)d_in[16];
    const float* W1  = (const float*)d_in[17];
    const float* bf1 = (const float*)d_in[18];
    const float* W2  = (const float*)d_in[19];
    const float* bf2 = (const float*)d_in[20];
    float* out = (float*)d_out;

    char* W = (char*)d_ws;
    u16* WqT  = (u16*)(W + 0);
    u16* WkvT = (u16*)(W + 1179648);
    u16* WoT  = (u16*)(W + 3538944);
    u16* WmT  = (u16*)(W + 4718592);
    u16* W1T  = (u16*)(W + 5898240);
    u16* W2T  = (u16*)(W + 10616832);
    float* scores  = (float*)(W + 15335424);
    unsigned* mask = (unsigned*)(W + 15368192);
    float* ssum    = (float*)(W + 15400960);
    float* pooled  = (float*)(W + 15401216);
    float* pWm     = (float*)(W + 15413504);
    float* parts   = (float*)(W + 15425792);
    float* bkv     = (float*)(W + 15524096);
    float* bqs     = (float*)(W + 15530240);
    int* rowmap    = (int*)(W + 15533312);
    int* invmap    = (int*)(W + 15538432);
    u16* nb    = (u16*)(W + 15728640);
    u16* Y     = (u16*)(W + 28311552);
    u16* qcomp = (u16*)(W + 53477376);
    u16* ctxc  = (u16*)(W + 55443456);
    float* attnc = (float*)(W + 57409536);
    u16* VT    = (u16*)(W + 61341696);
    float* h   = (float*)(W + 28311552);
    u16* n2b   = (u16*)(W + 15728640);
    u16* mid   = (u16*)(W + 53477376);

    wconv_all<<<7488, 256, 0, stream>>>(Wq, Wk, Wv, Wo, Wm, W1, W2,
                                        WqT, WkvT, WoT, WmT, W1T, W2T);
    biasprep<<<3, 256, 0, stream>>>(bq, bk, bv, bqs, bkv);

    const int NT = B_ * L_;
    ln_kernel<true><<<NT, 256, 0, stream>>>(x, g1, b1, Wr, br, nb, scores);
    topk_kernel<<<B_, 256, 0, stream>>>(scores, mask, ssum, rowmap, invmap);
    pooled_part<<<dim3(8, B_), 256, 0, stream>>>(scores, nb, parts);
    pooled_combine<<<dim3(3, B_), 256, 0, stream>>>(parts, ssum, pooled);
    pooledWm_kernel<<<dim3(3, B_), 256, 0, stream>>>(pooled, Wm, pWm);

    // dense KV projection -> Y [8192][1536]  (64 m x 12 n = 768 blocks)
    mfma_gemm<1, false, 128><<<768, 256, 0, stream>>>(nb, WkvT, bkv, Y, 1536, 768, 12,
        nullptr, nullptr, nullptr, nullptr, nullptr, nullptr, nullptr, nullptr);
    // gathered Q projection (scaled 1/8) -> qcomp [1280][768]  (20 m x 6 n = 120)
    mfma_gemm<1, true, 64><<<120, 256, 0, stream>>>(nb, WqT, bqs, qcomp, 768, 768, 6,
        nullptr, nullptr, nullptr, nullptr, nullptr, nullptr, rowmap, nullptr);
    // V transpose -> VT
    vtrans<<<dim3(32, H_, B_), 256, 0, stream>>>(Y + 768, VT, 1536);
    // compacted attention -> ctxc
    attn2<<<dim3(KPAD / 64, H_, B_), 256, 0, stream>>>(qcomp, Y, VT, ctxc);
    // attn_out (compact) = ctxc @ Wo + bo  (20 m x 6 n = 120)
    mfma_gemm<0, false, 64><<<120, 256, 0, stream>>>(ctxc, WoT, bo, attnc, 768, 768, 6,
        nullptr, nullptr, nullptr, nullptr, nullptr, nullptr, nullptr, nullptr);
    // h = x + where(mask, attnc[inv], normed@Wm + bm + s*pWm)  (128 m x 6 n = 768)
    mfma_gemm<3, false, 64><<<768, 256, 0, stream>>>(nb, WmT, bm, h, 768, 768, 6,
        x, mask, attnc, scores, pWm, nullptr, nullptr, invmap);
    // LN2 -> n2b
    ln_kernel<false><<<NT, 256, 0, stream>>>(h, g2, b2, nullptr, nullptr, n2b, nullptr);
    // FFN1 (64 m x 24 n = 1536)
    mfma_gemm<2, false, 128><<<1536, 256, 0, stream>>>(n2b, W1T, bf1, mid, 3072, 768, 24,
        nullptr, nullptr, nullptr, nullptr, nullptr, nullptr, nullptr, nullptr);
    // FFN2 (128 m x 6 n = 768)
    mfma_gemm<4, false, 64><<<768, 256, 0, stream>>>(mid, W2T, bf2, out, 768, 3072, 6,
        nullptr, nullptr, nullptr, nullptr, nullptr, h, nullptr, nullptr);
}

// Round 6
// 529.506 us; speedup vs baseline: 8.9910x; 1.0123x over previous
//
#include <hip/hip_runtime.h>
#include <math.h>

#define B_ 4
#define L_ 2048
#define D_ 768
#define H_ 12
#define F_ 3072
#define KTOP 307
#define KPAD 320
#define LN_EPS 1e-5f

typedef unsigned int u32;
typedef unsigned short u16;
using bf16x8 = __attribute__((ext_vector_type(8))) short;
using f32x4  = __attribute__((ext_vector_type(4))) float;

#define AS1 __attribute__((address_space(1)))
#define AS3 __attribute__((address_space(3)))

__device__ __forceinline__ void gl16(const void* g, void* l) {
    __builtin_amdgcn_global_load_lds((const AS1 u32*)g, (AS3 u32*)l, 16, 0, 0);
}
// explicit drain of the global_load_lds queue before barriers
__device__ __forceinline__ void wait_vm0() {
    asm volatile("s_waitcnt vmcnt(0)" ::: "memory");
}
__device__ __forceinline__ u16 f2bf(float f) {
    u32 u = __float_as_uint(f);
    return (u16)((u + 0x7fff + ((u >> 16) & 1)) >> 16);
}
__device__ __forceinline__ float bf2f(u16 s) {
    return __uint_as_float(((u32)s) << 16);
}
// tanh-form GELU: v*sigmoid(1.5957691*(v+0.044715 v^3)); |err vs erf-GELU| <= ~1e-3,
// far below the bf16 quantization applied to the result. ~8 VALU ops vs ~30 for erff.
__device__ __forceinline__ float gelu_tanh(float v) {
    float u = v * v * v;
    float z = fmaf(u, 0.0713548163f, 1.59576912f * v);
    float s = __builtin_amdgcn_rcpf(1.0f + __expf(-z));
    return v * s;
}

// ---------------- block reduce (256 threads) ----------------
__device__ __forceinline__ float blk_reduce_sum(float v, float* red) {
    #pragma unroll
    for (int off = 32; off; off >>= 1) v += __shfl_xor(v, off, 64);
    __syncthreads();
    if ((threadIdx.x & 63) == 0) red[threadIdx.x >> 6] = v;
    __syncthreads();
    return red[0] + red[1] + red[2] + red[3];
}

// ---------------- LN -> bf16 normed (+ optional fp32 router score) ----------------
template <bool SCORE>
__global__ __launch_bounds__(256) void ln_kernel(
    const float* __restrict__ x, const float* __restrict__ g,
    const float* __restrict__ be, const float* __restrict__ Wr,
    const float* __restrict__ brp, u16* __restrict__ outn,
    float* __restrict__ scores)
{
    __shared__ float red[4];
    const int t = blockIdx.x;
    const int tid = threadIdx.x;
    const float* xr = x + (size_t)t * D_;
    float v0 = xr[tid], v1 = xr[tid + 256], v2 = xr[tid + 512];
    float mean = blk_reduce_sum(v0 + v1 + v2, red) * (1.0f / 768.0f);
    float d0 = v0 - mean, d1 = v1 - mean, d2 = v2 - mean;
    __syncthreads();
    float var = blk_reduce_sum(d0 * d0 + d1 * d1 + d2 * d2, red) * (1.0f / 768.0f);
    float inv = 1.0f / sqrtf(var + LN_EPS);
    float n0 = d0 * inv * g[tid] + be[tid];
    float n1 = d1 * inv * g[tid + 256] + be[tid + 256];
    float n2 = d2 * inv * g[tid + 512] + be[tid + 512];
    u16* orow = outn + (size_t)t * D_;
    orow[tid] = f2bf(n0); orow[tid + 256] = f2bf(n1); orow[tid + 512] = f2bf(n2);
    if (SCORE) {
        __syncthreads();
        float dot = blk_reduce_sum(n0 * Wr[tid] + n1 * Wr[tid + 256] + n2 * Wr[tid + 512], red);
        if (tid == 0) scores[t] = 1.0f / (1.0f + expf(-(dot + brp[0])));
    }
}

// ---------------- top-k + compaction maps + score-sum ----------------
__global__ __launch_bounds__(256) void topk_kernel(
    const float* __restrict__ scores, unsigned* __restrict__ mask,
    float* __restrict__ ssum, int* __restrict__ rowmap, int* __restrict__ inv)
{
    __shared__ unsigned long long keys[L_];
    __shared__ float red[4];
    const int b = blockIdx.x, tid = threadIdx.x;
    float local = 0.f;
    for (int i = tid; i < L_; i += 256) {
        float sc = scores[b * L_ + i];
        keys[i] = ((unsigned long long)__float_as_uint(sc) << 32) | (unsigned)i;
        local += sc;
    }
    float tot = blk_reduce_sum(local, red);
    if (tid == 0) ssum[b] = tot;
    __syncthreads();
    for (int size = 2; size <= L_; size <<= 1) {
        for (int stride = size >> 1; stride > 0; stride >>= 1) {
            for (int i = tid; i < L_; i += 256) {
                int j = i ^ stride;
                if (j > i) {
                    bool up = ((i & size) == 0);
                    unsigned long long a = keys[i], c = keys[j];
                    if ((a > c) == up) { keys[i] = c; keys[j] = a; }
                }
            }
            __syncthreads();
        }
    }
    unsigned long long cutoff = keys[KTOP - 1];
    for (int i = tid; i < L_; i += 256) {
        float sc = scores[b * L_ + i];
        unsigned long long k = ((unsigned long long)__float_as_uint(sc) << 32) | (unsigned)i;
        bool in = (k <= cutoff);
        mask[b * L_ + i] = in ? 1u : 0u;
        if (!in) inv[b * L_ + i] = 0;
    }
    for (int i = tid; i < KTOP; i += 256) {
        int tok = (int)(keys[i] & 0xffffffffULL);
        rowmap[b * KPAD + i] = b * L_ + tok;
        inv[b * L_ + tok] = b * KPAD + i;
    }
    if (tid < KPAD - KTOP)
        rowmap[b * KPAD + KTOP + tid] = b * L_ + (int)(keys[0] & 0xffffffffULL);
}

// ---------------- pooled partials ----------------
__global__ __launch_bounds__(256) void pooled_part(
    const float* __restrict__ scores, const u16* __restrict__ nb,
    float* __restrict__ parts)
{
    const int lc = blockIdx.x, b = blockIdx.y, tid = threadIdx.x;
    float a0 = 0.f, a1 = 0.f, a2 = 0.f;
    for (int l = lc * 256; l < lc * 256 + 256; l++) {
        float s = scores[b * L_ + l];
        const u16* row = nb + (size_t)(b * L_ + l) * D_;
        a0 += s * bf2f(row[tid]);
        a1 += s * bf2f(row[tid + 256]);
        a2 += s * bf2f(row[tid + 512]);
    }
    float* p = parts + (size_t)(lc * B_ + b) * D_;
    p[tid] = a0; p[tid + 256] = a1; p[tid + 512] = a2;
}

// ---------------- fused: pooled = (sum parts)/ssum (LDS); pWm = pooled @ Wm ----------------
__global__ __launch_bounds__(256) void pooled_wm(
    const float* __restrict__ parts, const float* __restrict__ ssum,
    const float* __restrict__ Wm, float* __restrict__ pWm)
{
    __shared__ float pl[768];
    const int b = blockIdx.y, n0 = blockIdx.x * 256, tid = threadIdx.x;
    float inv = 1.0f / (ssum[b] + 1e-6f);
    for (int d = tid; d < 768; d += 256) {
        float s = 0.f;
        #pragma unroll
        for (int lc = 0; lc < 8; lc++) s += parts[(size_t)(lc * B_ + b) * D_ + d];
        pl[d] = s * inv;
    }
    __syncthreads();
    const int n = n0 + tid;
    float acc = 0.f;
    for (int k = 0; k < 768; k++) acc += pl[k] * Wm[(size_t)k * D_ + n];
    pWm[b * D_ + n] = acc;
}

// ---------------- fused weight convert+transpose (7 weights + biases, 1 launch) ----------------
__global__ __launch_bounds__(256) void wconv_all(
    const float* __restrict__ Wq, const float* __restrict__ Wk,
    const float* __restrict__ Wv, const float* __restrict__ Wo,
    const float* __restrict__ Wm, const float* __restrict__ W1,
    const float* __restrict__ W2,
    u16* __restrict__ WqT, u16* __restrict__ WkvT, u16* __restrict__ WoT,
    u16* __restrict__ WmT, u16* __restrict__ W1T, u16* __restrict__ W2T,
    const float* __restrict__ bq, const float* __restrict__ bk,
    const float* __restrict__ bv, float* __restrict__ bqs,
    float* __restrict__ bkv)
{
    __shared__ float t[32][33];
    int id = blockIdx.x;
    const int tid = threadIdx.x;
    if (id >= 7488) {   // bias-prep block
        for (int i = tid; i < 768; i += 256) {
            bqs[i] = bq[i] * 0.125f;
            bkv[i] = bk[i];
            bkv[768 + i] = bv[i];
        }
        return;
    }
    const float* src; u16* dst; int K, N, local; float sc = 1.f;
    if (id < 576)       { src = Wq; dst = WqT; K = 768; N = 768; local = id; sc = 0.125f; }
    else if (id < 1152) { src = Wk; dst = WkvT;            K = 768; N = 768; local = id - 576; }
    else if (id < 1728) { src = Wv; dst = WkvT + 768 * 768; K = 768; N = 768; local = id - 1152; }
    else if (id < 2304) { src = Wo; dst = WoT; K = 768; N = 768; local = id - 1728; }
    else if (id < 2880) { src = Wm; dst = WmT; K = 768; N = 768; local = id - 2304; }
    else if (id < 5184) { src = W1; dst = W1T; K = 768; N = 3072; local = id - 2880; }
    else                { src = W2; dst = W2T; K = 3072; N = 768; local = id - 5184; }
    const int ntiles = N >> 5;
    const int n0 = (local % ntiles) * 32, k0 = (local / ntiles) * 32;
    const int tx = tid & 31, ty = tid >> 5;
    #pragma unroll
    for (int i = 0; i < 4; i++)
        t[ty + i * 8][tx] = src[(size_t)(k0 + ty + i * 8) * N + n0 + tx];
    __syncthreads();
    #pragma unroll
    for (int i = 0; i < 4; i++)
        dst[(size_t)(n0 + ty + i * 8) * K + k0 + tx] = f2bf(t[tx][ty + i * 8] * sc);
}

// ---------------- bf16 MFMA GEMM: C = epi(A[M][K] @ WT[N][K]^T + bias) ----------------
// EPI: 0 fp32, 1 bf16, 2 gelu->bf16, 3 merge->h fp32, 4 +hres fp32
// RMAP: A row gathered through rowmap[]
// TM: 128 (4 waves 2x2, 64x64 each) or 64 (4 waves 1x4, 64x32 each); TN fixed 128.
template <int EPI, bool RMAP, int TM>
__global__ __launch_bounds__(256) void mfma_gemm(
    const u16* __restrict__ A, const u16* __restrict__ Bt,
    const float* __restrict__ bias, void* __restrict__ Cout,
    int N, int K, int nbn,
    const float* __restrict__ x, const unsigned* __restrict__ msk,
    const float* __restrict__ attn, const float* __restrict__ scores,
    const float* __restrict__ pWm, const float* __restrict__ hres,
    const int* __restrict__ rowmap, const int* __restrict__ invmap)
{
    constexpr int NI = (TM == 128) ? 4 : 2;
    constexpr int ASLOTS = TM * 8 / 256;
    __shared__ u16 Asm[TM * 64];
    __shared__ u16 Bsm[128 * 64];
    const int tid = threadIdx.x;
    const int wave = tid >> 6, lane = tid & 63;
    const int quad = lane >> 4, l15 = lane & 15;

    const int wid = blockIdx.x;   // identity mapping (XCD swizzle dropped: R4 bisect)
    const int m0 = (wid / nbn) * TM, n0 = (wid % nbn) * 128;
    const int wm = (TM == 128) ? (wave >> 1) * 64 : 0;
    const int wn = (TM == 128) ? (wave & 1) * 64 : wave * 32;

    f32x4 acc[4][NI];
    #pragma unroll
    for (int i = 0; i < 4; i++)
        #pragma unroll
        for (int j = 0; j < NI; j++) acc[i][j] = 0.f;

    const u16* ap[ASLOTS]; const u16* bp[4];
    #pragma unroll
    for (int i = 0; i < ASLOTS; i++) {
        int s = i * 256 + tid;
        int row = s >> 3;
        int kq = (s & 7) ^ (row & 7);
        int arow = RMAP ? rowmap[m0 + row] : (m0 + row);
        ap[i] = A + (size_t)arow * K + kq * 8;
    }
    #pragma unroll
    for (int i = 0; i < 4; i++) {
        int s = i * 256 + tid;
        int row = s >> 3;
        int kq = (s & 7) ^ (row & 7);
        bp[i] = Bt + (size_t)(n0 + row) * K + kq * 8;
    }

    for (int k0 = 0; k0 < K; k0 += 64) {
        #pragma unroll
        for (int i = 0; i < ASLOTS; i++) {
            gl16(ap[i], &Asm[(i * 256 + wave * 64) * 8]);
            ap[i] += 64;
        }
        #pragma unroll
        for (int i = 0; i < 4; i++) {
            gl16(bp[i], &Bsm[(i * 256 + wave * 64) * 8]);
            bp[i] += 64;
        }
        wait_vm0();
        __syncthreads();
        #pragma unroll
        for (int kk = 0; kk < 2; kk++) {
            bf16x8 af[4], bf[NI];
            const int kq = kk * 4 + quad;
            #pragma unroll
            for (int mi = 0; mi < 4; mi++) {
                int row = wm + mi * 16 + l15;
                af[mi] = *(const bf16x8*)&Asm[(row * 8 + (kq ^ (row & 7))) * 8];
            }
            #pragma unroll
            for (int ni = 0; ni < NI; ni++) {
                int row = wn + ni * 16 + l15;
                bf[ni] = *(const bf16x8*)&Bsm[(row * 8 + (kq ^ (row & 7))) * 8];
            }
            #pragma unroll
            for (int mi = 0; mi < 4; mi++)
                #pragma unroll
                for (int ni = 0; ni < NI; ni++)
                    acc[mi][ni] = __builtin_amdgcn_mfma_f32_16x16x32_bf16(
                        af[mi], bf[ni], acc[mi][ni], 0, 0, 0);
        }
        __syncthreads();
    }

    #pragma unroll
    for (int mi = 0; mi < 4; mi++) {
        #pragma unroll
        for (int ni = 0; ni < NI; ni++) {
            #pragma unroll
            for (int r = 0; r < 4; r++) {
                int row = m0 + wm + mi * 16 + quad * 4 + r;
                int col = n0 + wn + ni * 16 + l15;
                float v = acc[mi][ni][r] + bias[col];
                size_t off = (size_t)row * N + col;
                if (EPI == 0) ((float*)Cout)[off] = v;
                else if (EPI == 1) ((u16*)Cout)[off] = f2bf(v);
                else if (EPI == 2) ((u16*)Cout)[off] = f2bf(gelu_tanh(v));
                else if (EPI == 3) {
                    float mix = v + scores[row] * pWm[(row >> 11) * D_ + col];
                    float sel = msk[row] ? attn[(size_t)invmap[row] * D_ + col] : mix;
                    ((float*)Cout)[off] = x[off] + sel;
                } else {
                    ((float*)Cout)[off] = v + hres[off];
                }
            }
        }
    }
}

// ---------------- V transpose: V[token][ld slice] -> VT[(b*H+h)*64+d][L] ----------------
__global__ __launch_bounds__(256) void vtrans(
    const u16* __restrict__ V, u16* __restrict__ VT, int ld)
{
    __shared__ u16 tl[64 * 72];
    const int tid = threadIdx.x;
    const int l0 = blockIdx.x * 64, h = blockIdx.y, b = blockIdx.z;
    const u16* src = V + h * 64;
    {
        int r = tid >> 3, ch = tid & 7;
        *(uint4*)&tl[r * 72 + ch * 8] =
            *(const uint4*)&src[(size_t)(b * L_ + l0 + r) * ld + ch * 8];
        int t2 = tid + 256; r = t2 >> 3; ch = t2 & 7;
        *(uint4*)&tl[r * 72 + ch * 8] =
            *(const uint4*)&src[(size_t)(b * L_ + l0 + r) * ld + ch * 8];
    }
    __syncthreads();
    int d = tid >> 2, lg = (tid & 3) * 16;
    u16* dst = VT + (size_t)((b * H_ + h) * 64 + d) * L_ + l0 + lg;
    union { u16 s[8]; uint4 v; } pk;
    #pragma unroll
    for (int j = 0; j < 8; j++) pk.s[j] = tl[(lg + j) * 72 + d];
    *(uint4*)dst = pk.v;
    #pragma unroll
    for (int j = 0; j < 8; j++) pk.s[j] = tl[(lg + 8 + j) * 72 + d];
    *(uint4*)(dst + 8) = pk.v;
}

// ---------------- compacted-Q MFMA attention, fixed-shift softmax ----------------
__global__ __launch_bounds__(256) void attn2(
    const u16* __restrict__ qcomp, const u16* __restrict__ Kg,
    const u16* __restrict__ VTg, u16* __restrict__ ctxc)
{
    __shared__ u16 Qs[64 * 64];
    __shared__ u16 Ks[64 * 64];
    __shared__ u16 Vs[64 * 64];
    __shared__ u16 Ps[4 * 16 * 72];
    const int tid = threadIdx.x, wave = tid >> 6, lane = tid & 63;
    const int quad = lane >> 4, l15 = lane & 15;
    const int qb = blockIdx.x, h = blockIdx.y, b = blockIdx.z;
    const int q0 = qb * 64;

    {
        int s0 = wave * 64 + lane;
        int r = s0 >> 3, c = (s0 & 7) ^ (r & 7);
        gl16(qcomp + (size_t)(b * KPAD + q0 + r) * D_ + h * 64 + c * 8,
             &Qs[(wave * 64) * 8]);
        int s1 = s0 + 256;
        int r1 = s1 >> 3, c1 = (s1 & 7) ^ (r1 & 7);
        gl16(qcomp + (size_t)(b * KPAD + q0 + r1) * D_ + h * 64 + c1 * 8,
             &Qs[(256 + wave * 64) * 8]);
    }
    const u16 *kp0, *kp1, *vp0, *vp1;
    {
        int s0 = wave * 64 + lane;
        int r = s0 >> 3, c = (s0 & 7) ^ (r & 7);
        kp0 = Kg + (size_t)(b * L_ + r) * 1536 + h * 64 + c * 8;
        vp0 = VTg + (size_t)((b * H_ + h) * 64 + r) * L_ + c * 8;
        int s1 = s0 + 256;
        int r1 = s1 >> 3, c1 = (s1 & 7) ^ (r1 & 7);
        kp1 = Kg + (size_t)(b * L_ + r1) * 1536 + h * 64 + c1 * 8;
        vp1 = VTg + (size_t)((b * H_ + h) * 64 + r1) * L_ + c1 * 8;
    }
    wait_vm0();
    __syncthreads();
    bf16x8 qf0, qf1;
    {
        int row = wave * 16 + l15;
        qf0 = *(const bf16x8*)&Qs[(row * 8 + ((quad)     ^ (row & 7))) * 8];
        qf1 = *(const bf16x8*)&Qs[(row * 8 + ((4 + quad) ^ (row & 7))) * 8];
    }
    f32x4 accO[4]; float lp[4];
    #pragma unroll
    for (int i = 0; i < 4; i++) { accO[i] = 0.f; lp[i] = 0.f; }
    u16* Psw = Ps + wave * 16 * 72;

    for (int kt = 0; kt < L_; kt += 64) {
        gl16(kp0, &Ks[(wave * 64) * 8]);        kp0 += (size_t)64 * 1536;
        gl16(kp1, &Ks[(256 + wave * 64) * 8]);  kp1 += (size_t)64 * 1536;
        gl16(vp0, &Vs[(wave * 64) * 8]);        vp0 += 64;
        gl16(vp1, &Vs[(256 + wave * 64) * 8]);  vp1 += 64;
        wait_vm0();
        __syncthreads();

        f32x4 accS[4];
        #pragma unroll
        for (int ni = 0; ni < 4; ni++) accS[ni] = 0.f;
        #pragma unroll
        for (int kk = 0; kk < 2; kk++) {
            const int kq = kk * 4 + quad;
            #pragma unroll
            for (int ni = 0; ni < 4; ni++) {
                int row = ni * 16 + l15;
                bf16x8 kf = *(const bf16x8*)&Ks[(row * 8 + (kq ^ (row & 7))) * 8];
                accS[ni] = __builtin_amdgcn_mfma_f32_16x16x32_bf16(
                    kk ? qf1 : qf0, kf, accS[ni], 0, 0, 0);
            }
        }
        #pragma unroll
        for (int ni = 0; ni < 4; ni++) {
            #pragma unroll
            for (int r = 0; r < 4; r++) {
                float p = __expf(accS[ni][r]);
                lp[r] += p;
                Psw[(quad * 4 + r) * 72 + ni * 16 + l15] = f2bf(p);
            }
        }
        #pragma unroll
        for (int kk = 0; kk < 2; kk++) {
            bf16x8 pf = *(const bf16x8*)&Psw[l15 * 72 + kk * 32 + quad * 8];
            const int kq = kk * 4 + quad;
            #pragma unroll
            for (int ni = 0; ni < 4; ni++) {
                int row = ni * 16 + l15;
                bf16x8 vf = *(const bf16x8*)&Vs[(row * 8 + (kq ^ (row & 7))) * 8];
                accO[ni] = __builtin_amdgcn_mfma_f32_16x16x32_bf16(pf, vf, accO[ni], 0, 0, 0);
            }
        }
        __syncthreads();
    }

    float invl[4];
    #pragma unroll
    for (int r = 0; r < 4; r++) {
        float s = lp[r];
        s += __shfl_xor(s, 1, 64); s += __shfl_xor(s, 2, 64);
        s += __shfl_xor(s, 4, 64); s += __shfl_xor(s, 8, 64);
        invl[r] = 1.0f / s;
    }
    #pragma unroll
    for (int ni = 0; ni < 4; ni++) {
        #pragma unroll
        for (int r = 0; r < 4; r++) {
            int ql = q0 + wave * 16 + quad * 4 + r;
            if (ql < KTOP)
                ctxc[(size_t)(b * KPAD + ql) * D_ + h * 64 + ni * 16 + l15] =
                    f2bf(accO[ni][r] * invl[r]);
        }
    }
}

// ---------------- launch ----------------
extern "C" void kernel_launch(void* const* d_in, const int* in_sizes, int n_in,
                              void* d_out, int out_size, void* d_ws, size_t ws_size,
                              hipStream_t stream)
{
    const float* x   = (const float*)d_in[0];
    const float* g1  = (const float*)d_in[1];
    const float* b1  = (const float*)d_in[2];
    const float* g2  = (const float*)d_in[3];
    const float* b2  = (const float*)d_in[4];
    const float* Wr  = (const float*)d_in[5];
    const float* br  = (const float*)d_in[6];
    const float* Wq  = (const float*)d_in[7];
    const float* bq  = (const float*)d_in[8];
    const float* Wk  = (const float*)d_in[9];
    const float* bk  = (const float*)d_in[10];
    const float* Wv  = (const float*)d_in[11];
    const float* bv  = (const float*)d_in[12];
    const float* Wo  = (const float*)d_in[13];
    const float* bo  = (const float*)d_in[14];
    const float* Wm  = (const float*)d_in[15];
    const float* bm  = (const float*)d_in[16];
    const float* W1  = (const float*)d_in[17];
    const float* bf1 = (const float*)d_in[18];
    const float* W2  = (const float*)d_in[19];
    const float* bf2 = (const float*)d_in[20];
    float* out = (float*)d_out;

    char* W = (char*)d_ws;
    u16* WqT  = (u16*)(W + 0);
    u16* WkvT = (u16*)(W + 1179648);
    u16* WoT  = (u16*)(W + 3538944);
    u16* WmT  = (u16*)(W + 4718592);
    u16* W1T  = (u16*)(W + 5898240);
    u16* W2T  = (u16*)(W + 10616832);
    float* scores  = (float*)(W + 15335424);
    unsigned* mask = (unsigned*)(W + 15368192);
    float* ssum    = (float*)(W + 15400960);
    float* pWm     = (float*)(W + 15413504);
    float* parts   = (float*)(W + 15425792);
    float* bkv     = (float*)(W + 15524096);
    float* bqs     = (float*)(W + 15530240);
    int* rowmap    = (int*)(W + 15533312);
    int* invmap    = (int*)(W + 15538432);
    u16* nb    = (u16*)(W + 15728640);
    u16* Y     = (u16*)(W + 28311552);
    u16* qcomp = (u16*)(W + 53477376);
    u16* ctxc  = (u16*)(W + 55443456);
    float* attnc = (float*)(W + 57409536);
    u16* VT    = (u16*)(W + 61341696);
    float* h   = (float*)(W + 28311552);
    u16* n2b   = (u16*)(W + 15728640);
    u16* mid   = (u16*)(W + 53477376);

    wconv_all<<<7489, 256, 0, stream>>>(Wq, Wk, Wv, Wo, Wm, W1, W2,
                                        WqT, WkvT, WoT, WmT, W1T, W2T,
                                        bq, bk, bv, bqs, bkv);

    const int NT = B_ * L_;
    ln_kernel<true><<<NT, 256, 0, stream>>>(x, g1, b1, Wr, br, nb, scores);
    topk_kernel<<<B_, 256, 0, stream>>>(scores, mask, ssum, rowmap, invmap);
    pooled_part<<<dim3(8, B_), 256, 0, stream>>>(scores, nb, parts);
    pooled_wm<<<dim3(3, B_), 256, 0, stream>>>(parts, ssum, Wm, pWm);

    // dense KV projection -> Y [8192][1536]  (64 m x 12 n = 768 blocks)
    mfma_gemm<1, false, 128><<<768, 256, 0, stream>>>(nb, WkvT, bkv, Y, 1536, 768, 12,
        nullptr, nullptr, nullptr, nullptr, nullptr, nullptr, nullptr, nullptr);
    // gathered Q projection (scaled 1/8) -> qcomp [1280][768]  (20 m x 6 n = 120)
    mfma_gemm<1, true, 64><<<120, 256, 0, stream>>>(nb, WqT, bqs, qcomp, 768, 768, 6,
        nullptr, nullptr, nullptr, nullptr, nullptr, nullptr, rowmap, nullptr);
    // V transpose -> VT
    vtrans<<<dim3(32, H_, B_), 256, 0, stream>>>(Y + 768, VT, 1536);
    // compacted attention -> ctxc
    attn2<<<dim3(KPAD / 64, H_, B_), 256, 0, stream>>>(qcomp, Y, VT, ctxc);
    // attn_out (compact) = ctxc @ Wo + bo  (20 m x 6 n = 120)
    mfma_gemm<0, false, 64><<<120, 256, 0, stream>>>(ctxc, WoT, bo, attnc, 768, 768, 6,
        nullptr, nullptr, nullptr, nullptr, nullptr, nullptr, nullptr, nullptr);
    // h = x + where(mask, attnc[inv], normed@Wm + bm + s*pWm)  (128 m x 6 n = 768)
    mfma_gemm<3, false, 64><<<768, 256, 0, stream>>>(nb, WmT, bm, h, 768, 768, 6,
        x, mask, attnc, scores, pWm, nullptr, nullptr, invmap);
    // LN2 -> n2b
    ln_kernel<false><<<NT, 256, 0, stream>>>(h, g2, b2, nullptr, nullptr, n2b, nullptr);
    // FFN1 (64 m x 24 n = 1536)
    mfma_gemm<2, false, 128><<<1536, 256, 0, stream>>>(n2b, W1T, bf1, mid, 3072, 768, 24,
        nullptr, nullptr, nullptr, nullptr, nullptr, nullptr, nullptr, nullptr);
    // FFN2 (128 m x 6 n = 768)
    mfma_gemm<4, false, 64><<<768, 256, 0, stream>>>(mid, W2T, bf2, out, 768, 3072, 6,
        nullptr, nullptr, nullptr, nullptr, nullptr, h, nullptr, nullptr);
}

// Round 7
// 469.601 us; speedup vs baseline: 10.1379x; 1.1276x over previous
//
#include <hip/hip_runtime.h>
#include <math.h>

#define B_ 4
#define L_ 2048
#define D_ 768
#define H_ 12
#define F_ 3072
#define KTOP 307
#define KPAD 320
#define LN_EPS 1e-5f

typedef unsigned int u32;
typedef unsigned short u16;
using bf16x8 = __attribute__((ext_vector_type(8))) short;
using f32x4  = __attribute__((ext_vector_type(4))) float;

#define AS1 __attribute__((address_space(1)))
#define AS3 __attribute__((address_space(3)))

__device__ __forceinline__ void gl16(const void* g, void* l) {
    __builtin_amdgcn_global_load_lds((const AS1 u32*)g, (AS3 u32*)l, 16, 0, 0);
}
// explicit drain of the global_load_lds queue before barriers
__device__ __forceinline__ void wait_vm0() {
    asm volatile("s_waitcnt vmcnt(0)" ::: "memory");
}
__device__ __forceinline__ u16 f2bf(float f) {
    u32 u = __float_as_uint(f);
    return (u16)((u + 0x7fff + ((u >> 16) & 1)) >> 16);
}
__device__ __forceinline__ float bf2f(u16 s) {
    return __uint_as_float(((u32)s) << 16);
}
// tanh-form GELU: ~8 VALU ops vs ~30 for erff; |err| <= ~1e-3 << bf16 quantization.
__device__ __forceinline__ float gelu_tanh(float v) {
    float u = v * v * v;
    float z = fmaf(u, 0.0713548163f, 1.59576912f * v);
    float s = __builtin_amdgcn_rcpf(1.0f + __expf(-z));
    return v * s;
}

// ---------------- block reduce (256 threads) ----------------
__device__ __forceinline__ float blk_reduce_sum(float v, float* red) {
    #pragma unroll
    for (int off = 32; off; off >>= 1) v += __shfl_xor(v, off, 64);
    __syncthreads();
    if ((threadIdx.x & 63) == 0) red[threadIdx.x >> 6] = v;
    __syncthreads();
    return red[0] + red[1] + red[2] + red[3];
}

// ---------------- LN -> bf16 normed (+ optional fp32 router score) ----------------
template <bool SCORE>
__global__ __launch_bounds__(256) void ln_kernel(
    const float* __restrict__ x, const float* __restrict__ g,
    const float* __restrict__ be, const float* __restrict__ Wr,
    const float* __restrict__ brp, u16* __restrict__ outn,
    float* __restrict__ scores)
{
    __shared__ float red[4];
    const int t = blockIdx.x;
    const int tid = threadIdx.x;
    const float* xr = x + (size_t)t * D_;
    float v0 = xr[tid], v1 = xr[tid + 256], v2 = xr[tid + 512];
    float mean = blk_reduce_sum(v0 + v1 + v2, red) * (1.0f / 768.0f);
    float d0 = v0 - mean, d1 = v1 - mean, d2 = v2 - mean;
    __syncthreads();
    float var = blk_reduce_sum(d0 * d0 + d1 * d1 + d2 * d2, red) * (1.0f / 768.0f);
    float inv = 1.0f / sqrtf(var + LN_EPS);
    float n0 = d0 * inv * g[tid] + be[tid];
    float n1 = d1 * inv * g[tid + 256] + be[tid + 256];
    float n2 = d2 * inv * g[tid + 512] + be[tid + 512];
    u16* orow = outn + (size_t)t * D_;
    orow[tid] = f2bf(n0); orow[tid + 256] = f2bf(n1); orow[tid + 512] = f2bf(n2);
    if (SCORE) {
        __syncthreads();
        float dot = blk_reduce_sum(n0 * Wr[tid] + n1 * Wr[tid + 256] + n2 * Wr[tid + 512], red);
        if (tid == 0) scores[t] = 1.0f / (1.0f + expf(-(dot + brp[0])));
    }
}

// ---------------- exact radix-select top-k (lowest KTOP scores) ----------------
// 1 block/batch, 1024 threads. u32 bit order == float order (scores > 0).
// Selection set identical to sorting composite keys (score_bits<<32)|index:
// all score<s*, plus lowest-index `want` among score==s*.
__global__ __launch_bounds__(1024) void topk_kernel(
    const float* __restrict__ scores, unsigned* __restrict__ mask,
    float* __restrict__ ssum, int* __restrict__ rowmap, int* __restrict__ inv)
{
    __shared__ u32 sb[L_];
    __shared__ u32 hist[256];
    __shared__ u32 wsum[16];
    __shared__ float redf[16];
    __shared__ u32 bcast[2];
    __shared__ u32 cnt_sel;
    const int b = blockIdx.x, tid = threadIdx.x;
    const int lane = tid & 63, wv = tid >> 6;

    if (tid == 0) cnt_sel = 0;
    float s0 = scores[b * L_ + tid];
    float s1 = scores[b * L_ + tid + 1024];
    sb[tid] = __float_as_uint(s0);
    sb[tid + 1024] = __float_as_uint(s1);
    float v = s0 + s1;
    #pragma unroll
    for (int o = 32; o; o >>= 1) v += __shfl_xor(v, o, 64);
    if (lane == 0) redf[wv] = v;
    __syncthreads();
    if (tid == 0) {
        float t = 0.f;
        #pragma unroll
        for (int w = 0; w < 16; w++) t += redf[w];
        ssum[b] = t;
    }

    u32 want = KTOP, prefix = 0;
    #pragma unroll
    for (int pass = 0; pass < 4; pass++) {
        const int shift = 24 - pass * 8;
        if (tid < 256) hist[tid] = 0;
        __syncthreads();
        u32 x0 = sb[tid], x1 = sb[tid + 1024];
        if (pass == 0 || (x0 >> (shift + 8)) == prefix) atomicAdd(&hist[(x0 >> shift) & 255], 1u);
        if (pass == 0 || (x1 >> (shift + 8)) == prefix) atomicAdd(&hist[(x1 >> shift) & 255], 1u);
        __syncthreads();
        u32 c = 0, inc = 0;
        if (tid < 256) {
            c = hist[tid];
            inc = c;
            #pragma unroll
            for (int o = 1; o < 64; o <<= 1) {
                u32 t = __shfl_up(inc, o, 64);
                if (lane >= o) inc += t;
            }
            if (lane == 63) wsum[wv] = inc;
        }
        __syncthreads();
        if (tid < 256) {
            u32 base = 0;
            #pragma unroll
            for (int w = 0; w < 4; w++) if (w < wv) base += wsum[w];
            u32 incl = base + inc;
            u32 excl = incl - c;
            if (excl < want && want <= incl) {
                bcast[0] = (u32)tid;
                bcast[1] = want - excl;
            }
        }
        __syncthreads();
        prefix = (prefix << 8) | bcast[0];
        want = bcast[1];
    }

    // tie-break among score==s* by lowest index: block prefix-scan of eq flags
    const u32 sstar = prefix;
    u32 a0 = sb[2 * tid], a1 = sb[2 * tid + 1];
    u32 e0 = (a0 == sstar) ? 1u : 0u, e1 = (a1 == sstar) ? 1u : 0u;
    u32 ps = e0 + e1, inc2 = ps;
    #pragma unroll
    for (int o = 1; o < 64; o <<= 1) {
        u32 t = __shfl_up(inc2, o, 64);
        if (lane >= o) inc2 += t;
    }
    __syncthreads();          // wsum reuse: ensure pass-3 readers done
    if (lane == 63) wsum[wv] = inc2;
    __syncthreads();
    u32 base = 0;
    #pragma unroll
    for (int w = 0; w < 16; w++) if (w < wv) base += wsum[w];
    u32 excl0 = base + inc2 - ps;   // eq-rank of position 2*tid
    {
        int i = 2 * tid;
        bool sel = (a0 < sstar) || (e0 && (excl0 < want));
        mask[b * L_ + i] = sel ? 1u : 0u;
        int invv = 0;
        if (sel) {
            u32 slot = atomicAdd(&cnt_sel, 1u);
            rowmap[b * KPAD + slot] = b * L_ + i;
            invv = b * KPAD + (int)slot;
        }
        inv[b * L_ + i] = invv;
    }
    {
        int i = 2 * tid + 1;
        u32 r1 = excl0 + e0;
        bool sel = (a1 < sstar) || (e1 && (r1 < want));
        mask[b * L_ + i] = sel ? 1u : 0u;
        int invv = 0;
        if (sel) {
            u32 slot = atomicAdd(&cnt_sel, 1u);
            rowmap[b * KPAD + slot] = b * L_ + i;
            invv = b * KPAD + (int)slot;
        }
        inv[b * L_ + i] = invv;
    }
    if (tid < KPAD - KTOP)
        rowmap[b * KPAD + KTOP + tid] = b * L_;   // padding rows: any valid token
}

// ---------------- pooled partials ----------------
__global__ __launch_bounds__(256) void pooled_part(
    const float* __restrict__ scores, const u16* __restrict__ nb,
    float* __restrict__ parts)
{
    const int lc = blockIdx.x, b = blockIdx.y, tid = threadIdx.x;
    float a0 = 0.f, a1 = 0.f, a2 = 0.f;
    for (int l = lc * 256; l < lc * 256 + 256; l++) {
        float s = scores[b * L_ + l];
        const u16* row = nb + (size_t)(b * L_ + l) * D_;
        a0 += s * bf2f(row[tid]);
        a1 += s * bf2f(row[tid + 256]);
        a2 += s * bf2f(row[tid + 512]);
    }
    float* p = parts + (size_t)(lc * B_ + b) * D_;
    p[tid] = a0; p[tid + 256] = a1; p[tid + 512] = a2;
}

// ---------------- fused: pooled = (sum parts)/ssum (LDS); pWm = pooled @ Wm ----------------
__global__ __launch_bounds__(256) void pooled_wm(
    const float* __restrict__ parts, const float* __restrict__ ssum,
    const float* __restrict__ Wm, float* __restrict__ pWm)
{
    __shared__ float pl[768];
    const int b = blockIdx.y, n0 = blockIdx.x * 256, tid = threadIdx.x;
    float inv = 1.0f / (ssum[b] + 1e-6f);
    for (int d = tid; d < 768; d += 256) {
        float s = 0.f;
        #pragma unroll
        for (int lc = 0; lc < 8; lc++) s += parts[(size_t)(lc * B_ + b) * D_ + d];
        pl[d] = s * inv;
    }
    __syncthreads();
    const int n = n0 + tid;
    float acc = 0.f;
    for (int k = 0; k < 768; k++) acc += pl[k] * Wm[(size_t)k * D_ + n];
    pWm[b * D_ + n] = acc;
}

// ---------------- fused weight convert+transpose (7 weights + biases, 1 launch) ----------------
__global__ __launch_bounds__(256) void wconv_all(
    const float* __restrict__ Wq, const float* __restrict__ Wk,
    const float* __restrict__ Wv, const float* __restrict__ Wo,
    const float* __restrict__ Wm, const float* __restrict__ W1,
    const float* __restrict__ W2,
    u16* __restrict__ WqT, u16* __restrict__ WkvT, u16* __restrict__ WoT,
    u16* __restrict__ WmT, u16* __restrict__ W1T, u16* __restrict__ W2T,
    const float* __restrict__ bq, const float* __restrict__ bk,
    const float* __restrict__ bv, float* __restrict__ bqs,
    float* __restrict__ bkv)
{
    __shared__ float t[32][33];
    int id = blockIdx.x;
    const int tid = threadIdx.x;
    if (id >= 7488) {   // bias-prep block
        for (int i = tid; i < 768; i += 256) {
            bqs[i] = bq[i] * 0.125f;
            bkv[i] = bk[i];
            bkv[768 + i] = bv[i];
        }
        return;
    }
    const float* src; u16* dst; int K, N, local; float sc = 1.f;
    if (id < 576)       { src = Wq; dst = WqT; K = 768; N = 768; local = id; sc = 0.125f; }
    else if (id < 1152) { src = Wk; dst = WkvT;            K = 768; N = 768; local = id - 576; }
    else if (id < 1728) { src = Wv; dst = WkvT + 768 * 768; K = 768; N = 768; local = id - 1152; }
    else if (id < 2304) { src = Wo; dst = WoT; K = 768; N = 768; local = id - 1728; }
    else if (id < 2880) { src = Wm; dst = WmT; K = 768; N = 768; local = id - 2304; }
    else if (id < 5184) { src = W1; dst = W1T; K = 768; N = 3072; local = id - 2880; }
    else                { src = W2; dst = W2T; K = 3072; N = 768; local = id - 5184; }
    const int ntiles = N >> 5;
    const int n0 = (local % ntiles) * 32, k0 = (local / ntiles) * 32;
    const int tx = tid & 31, ty = tid >> 5;
    #pragma unroll
    for (int i = 0; i < 4; i++)
        t[ty + i * 8][tx] = src[(size_t)(k0 + ty + i * 8) * N + n0 + tx];
    __syncthreads();
    #pragma unroll
    for (int i = 0; i < 4; i++)
        dst[(size_t)(n0 + ty + i * 8) * K + k0 + tx] = f2bf(t[tx][ty + i * 8] * sc);
}

// ---------------- bf16 MFMA GEMM: C = epi(A[M][K] @ WT[N][K]^T + bias) ----------------
// EPI: 0 fp32, 1 bf16, 2 gelu->bf16, 3 merge->h fp32, 4 +hres fp32
// RMAP: A row gathered through rowmap[]
// TM: 128 (4 waves 2x2, 64x64 each) or 64 (4 waves 1x4, 64x32 each); TN fixed 128.
template <int EPI, bool RMAP, int TM>
__global__ __launch_bounds__(256) void mfma_gemm(
    const u16* __restrict__ A, const u16* __restrict__ Bt,
    const float* __restrict__ bias, void* __restrict__ Cout,
    int N, int K, int nbn,
    const float* __restrict__ x, const unsigned* __restrict__ msk,
    const float* __restrict__ attn, const float* __restrict__ scores,
    const float* __restrict__ pWm, const float* __restrict__ hres,
    const int* __restrict__ rowmap, const int* __restrict__ invmap)
{
    constexpr int NI = (TM == 128) ? 4 : 2;
    constexpr int ASLOTS = TM * 8 / 256;
    __shared__ u16 Asm[TM * 64];
    __shared__ u16 Bsm[128 * 64];
    const int tid = threadIdx.x;
    const int wave = tid >> 6, lane = tid & 63;
    const int quad = lane >> 4, l15 = lane & 15;

    const int wid = blockIdx.x;   // identity mapping (XCD swizzle dropped: R4 bisect)
    const int m0 = (wid / nbn) * TM, n0 = (wid % nbn) * 128;
    const int wm = (TM == 128) ? (wave >> 1) * 64 : 0;
    const int wn = (TM == 128) ? (wave & 1) * 64 : wave * 32;

    f32x4 acc[4][NI];
    #pragma unroll
    for (int i = 0; i < 4; i++)
        #pragma unroll
        for (int j = 0; j < NI; j++) acc[i][j] = 0.f;

    const u16* ap[ASLOTS]; const u16* bp[4];
    #pragma unroll
    for (int i = 0; i < ASLOTS; i++) {
        int s = i * 256 + tid;
        int row = s >> 3;
        int kq = (s & 7) ^ (row & 7);
        int arow = RMAP ? rowmap[m0 + row] : (m0 + row);
        ap[i] = A + (size_t)arow * K + kq * 8;
    }
    #pragma unroll
    for (int i = 0; i < 4; i++) {
        int s = i * 256 + tid;
        int row = s >> 3;
        int kq = (s & 7) ^ (row & 7);
        bp[i] = Bt + (size_t)(n0 + row) * K + kq * 8;
    }

    for (int k0 = 0; k0 < K; k0 += 64) {
        #pragma unroll
        for (int i = 0; i < ASLOTS; i++) {
            gl16(ap[i], &Asm[(i * 256 + wave * 64) * 8]);
            ap[i] += 64;
        }
        #pragma unroll
        for (int i = 0; i < 4; i++) {
            gl16(bp[i], &Bsm[(i * 256 + wave * 64) * 8]);
            bp[i] += 64;
        }
        wait_vm0();
        __syncthreads();
        #pragma unroll
        for (int kk = 0; kk < 2; kk++) {
            bf16x8 af[4], bf[NI];
            const int kq = kk * 4 + quad;
            #pragma unroll
            for (int mi = 0; mi < 4; mi++) {
                int row = wm + mi * 16 + l15;
                af[mi] = *(const bf16x8*)&Asm[(row * 8 + (kq ^ (row & 7))) * 8];
            }
            #pragma unroll
            for (int ni = 0; ni < NI; ni++) {
                int row = wn + ni * 16 + l15;
                bf[ni] = *(const bf16x8*)&Bsm[(row * 8 + (kq ^ (row & 7))) * 8];
            }
            #pragma unroll
            for (int mi = 0; mi < 4; mi++)
                #pragma unroll
                for (int ni = 0; ni < NI; ni++)
                    acc[mi][ni] = __builtin_amdgcn_mfma_f32_16x16x32_bf16(
                        af[mi], bf[ni], acc[mi][ni], 0, 0, 0);
        }
        __syncthreads();
    }

    #pragma unroll
    for (int mi = 0; mi < 4; mi++) {
        #pragma unroll
        for (int ni = 0; ni < NI; ni++) {
            #pragma unroll
            for (int r = 0; r < 4; r++) {
                int row = m0 + wm + mi * 16 + quad * 4 + r;
                int col = n0 + wn + ni * 16 + l15;
                float v = acc[mi][ni][r] + bias[col];
                size_t off = (size_t)row * N + col;
                if (EPI == 0) ((float*)Cout)[off] = v;
                else if (EPI == 1) ((u16*)Cout)[off] = f2bf(v);
                else if (EPI == 2) ((u16*)Cout)[off] = f2bf(gelu_tanh(v));
                else if (EPI == 3) {
                    float mix = v + scores[row] * pWm[(row >> 11) * D_ + col];
                    float sel = msk[row] ? attn[(size_t)invmap[row] * D_ + col] : mix;
                    ((float*)Cout)[off] = x[off] + sel;
                } else {
                    ((float*)Cout)[off] = v + hres[off];
                }
            }
        }
    }
}

// ---------------- V transpose: V[token][ld slice] -> VT[(b*H+h)*64+d][L] ----------------
__global__ __launch_bounds__(256) void vtrans(
    const u16* __restrict__ V, u16* __restrict__ VT, int ld)
{
    __shared__ u16 tl[64 * 72];
    const int tid = threadIdx.x;
    const int l0 = blockIdx.x * 64, h = blockIdx.y, b = blockIdx.z;
    const u16* src = V + h * 64;
    {
        int r = tid >> 3, ch = tid & 7;
        *(uint4*)&tl[r * 72 + ch * 8] =
            *(const uint4*)&src[(size_t)(b * L_ + l0 + r) * ld + ch * 8];
        int t2 = tid + 256; r = t2 >> 3; ch = t2 & 7;
        *(uint4*)&tl[r * 72 + ch * 8] =
            *(const uint4*)&src[(size_t)(b * L_ + l0 + r) * ld + ch * 8];
    }
    __syncthreads();
    int d = tid >> 2, lg = (tid & 3) * 16;
    u16* dst = VT + (size_t)((b * H_ + h) * 64 + d) * L_ + l0 + lg;
    union { u16 s[8]; uint4 v; } pk;
    #pragma unroll
    for (int j = 0; j < 8; j++) pk.s[j] = tl[(lg + j) * 72 + d];
    *(uint4*)dst = pk.v;
    #pragma unroll
    for (int j = 0; j < 8; j++) pk.s[j] = tl[(lg + 8 + j) * 72 + d];
    *(uint4*)(dst + 8) = pk.v;
}

// ---------------- compacted-Q MFMA attention, fixed-shift softmax ----------------
__global__ __launch_bounds__(256) void attn2(
    const u16* __restrict__ qcomp, const u16* __restrict__ Kg,
    const u16* __restrict__ VTg, u16* __restrict__ ctxc)
{
    __shared__ u16 Qs[64 * 64];
    __shared__ u16 Ks[64 * 64];
    __shared__ u16 Vs[64 * 64];
    __shared__ u16 Ps[4 * 16 * 72];
    const int tid = threadIdx.x, wave = tid >> 6, lane = tid & 63;
    const int quad = lane >> 4, l15 = lane & 15;
    const int qb = blockIdx.x, h = blockIdx.y, b = blockIdx.z;
    const int q0 = qb * 64;

    {
        int s0 = wave * 64 + lane;
        int r = s0 >> 3, c = (s0 & 7) ^ (r & 7);
        gl16(qcomp + (size_t)(b * KPAD + q0 + r) * D_ + h * 64 + c * 8,
             &Qs[(wave * 64) * 8]);
        int s1 = s0 + 256;
        int r1 = s1 >> 3, c1 = (s1 & 7) ^ (r1 & 7);
        gl16(qcomp + (size_t)(b * KPAD + q0 + r1) * D_ + h * 64 + c1 * 8,
             &Qs[(256 + wave * 64) * 8]);
    }
    const u16 *kp0, *kp1, *vp0, *vp1;
    {
        int s0 = wave * 64 + lane;
        int r = s0 >> 3, c = (s0 & 7) ^ (r & 7);
        kp0 = Kg + (size_t)(b * L_ + r) * 1536 + h * 64 + c * 8;
        vp0 = VTg + (size_t)((b * H_ + h) * 64 + r) * L_ + c * 8;
        int s1 = s0 + 256;
        int r1 = s1 >> 3, c1 = (s1 & 7) ^ (r1 & 7);
        kp1 = Kg + (size_t)(b * L_ + r1) * 1536 + h * 64 + c1 * 8;
        vp1 = VTg + (size_t)((b * H_ + h) * 64 + r1) * L_ + c1 * 8;
    }
    wait_vm0();
    __syncthreads();
    bf16x8 qf0, qf1;
    {
        int row = wave * 16 + l15;
        qf0 = *(const bf16x8*)&Qs[(row * 8 + ((quad)     ^ (row & 7))) * 8];
        qf1 = *(const bf16x8*)&Qs[(row * 8 + ((4 + quad) ^ (row & 7))) * 8];
    }
    f32x4 accO[4]; float lp[4];
    #pragma unroll
    for (int i = 0; i < 4; i++) { accO[i] = 0.f; lp[i] = 0.f; }
    u16* Psw = Ps + wave * 16 * 72;

    for (int kt = 0; kt < L_; kt += 64) {
        gl16(kp0, &Ks[(wave * 64) * 8]);        kp0 += (size_t)64 * 1536;
        gl16(kp1, &Ks[(256 + wave * 64) * 8]);  kp1 += (size_t)64 * 1536;
        gl16(vp0, &Vs[(wave * 64) * 8]);        vp0 += 64;
        gl16(vp1, &Vs[(256 + wave * 64) * 8]);  vp1 += 64;
        wait_vm0();
        __syncthreads();

        f32x4 accS[4];
        #pragma unroll
        for (int ni = 0; ni < 4; ni++) accS[ni] = 0.f;
        #pragma unroll
        for (int kk = 0; kk < 2; kk++) {
            const int kq = kk * 4 + quad;
            #pragma unroll
            for (int ni = 0; ni < 4; ni++) {
                int row = ni * 16 + l15;
                bf16x8 kf = *(const bf16x8*)&Ks[(row * 8 + (kq ^ (row & 7))) * 8];
                accS[ni] = __builtin_amdgcn_mfma_f32_16x16x32_bf16(
                    kk ? qf1 : qf0, kf, accS[ni], 0, 0, 0);
            }
        }
        #pragma unroll
        for (int ni = 0; ni < 4; ni++) {
            #pragma unroll
            for (int r = 0; r < 4; r++) {
                float p = __expf(accS[ni][r]);
                lp[r] += p;
                Psw[(quad * 4 + r) * 72 + ni * 16 + l15] = f2bf(p);
            }
        }
        #pragma unroll
        for (int kk = 0; kk < 2; kk++) {
            bf16x8 pf = *(const bf16x8*)&Psw[l15 * 72 + kk * 32 + quad * 8];
            const int kq = kk * 4 + quad;
            #pragma unroll
            for (int ni = 0; ni < 4; ni++) {
                int row = ni * 16 + l15;
                bf16x8 vf = *(const bf16x8*)&Vs[(row * 8 + (kq ^ (row & 7))) * 8];
                accO[ni] = __builtin_amdgcn_mfma_f32_16x16x32_bf16(pf, vf, accO[ni], 0, 0, 0);
            }
        }
        __syncthreads();
    }

    float invl[4];
    #pragma unroll
    for (int r = 0; r < 4; r++) {
        float s = lp[r];
        s += __shfl_xor(s, 1, 64); s += __shfl_xor(s, 2, 64);
        s += __shfl_xor(s, 4, 64); s += __shfl_xor(s, 8, 64);
        invl[r] = 1.0f / s;
    }
    #pragma unroll
    for (int ni = 0; ni < 4; ni++) {
        #pragma unroll
        for (int r = 0; r < 4; r++) {
            int ql = q0 + wave * 16 + quad * 4 + r;
            if (ql < KTOP)
                ctxc[(size_t)(b * KPAD + ql) * D_ + h * 64 + ni * 16 + l15] =
                    f2bf(accO[ni][r] * invl[r]);
        }
    }
}

// ---------------- launch ----------------
extern "C" void kernel_launch(void* const* d_in, const int* in_sizes, int n_in,
                              void* d_out, int out_size, void* d_ws, size_t ws_size,
                              hipStream_t stream)
{
    const float* x   = (const float*)d_in[0];
    const float* g1  = (const float*)d_in[1];
    const float* b1  = (const float*)d_in[2];
    const float* g2  = (const float*)d_in[3];
    const float* b2  = (const float*)d_in[4];
    const float* Wr  = (const float*)d_in[5];
    const float* br  = (const float*)d_in[6];
    const float* Wq  = (const float*)d_in[7];
    const float* bq  = (const float*)d_in[8];
    const float* Wk  = (const float*)d_in[9];
    const float* bk  = (const float*)d_in[10];
    const float* Wv  = (const float*)d_in[11];
    const float* bv  = (const float*)d_in[12];
    const float* Wo  = (const float*)d_in[13];
    const float* bo  = (const float*)d_in[14];
    const float* Wm  = (const float*)d_in[15];
    const float* bm  = (const float*)d_in[16];
    const float* W1  = (const float*)d_in[17];
    const float* bf1 = (const float*)d_in[18];
    const float* W2  = (const float*)d_in[19];
    const float* bf2 = (const float*)d_in[20];
    float* out = (float*)d_out;

    char* W = (char*)d_ws;
    u16* WqT  = (u16*)(W + 0);
    u16* WkvT = (u16*)(W + 1179648);
    u16* WoT  = (u16*)(W + 3538944);
    u16* WmT  = (u16*)(W + 4718592);
    u16* W1T  = (u16*)(W + 5898240);
    u16* W2T  = (u16*)(W + 10616832);
    float* scores  = (float*)(W + 15335424);
    unsigned* mask = (unsigned*)(W + 15368192);
    float* ssum    = (float*)(W + 15400960);
    float* pWm     = (float*)(W + 15413504);
    float* parts   = (float*)(W + 15425792);
    float* bkv     = (float*)(W + 15524096);
    float* bqs     = (float*)(W + 15530240);
    int* rowmap    = (int*)(W + 15533312);
    int* invmap    = (int*)(W + 15538432);
    u16* nb    = (u16*)(W + 15728640);
    u16* Y     = (u16*)(W + 28311552);
    u16* qcomp = (u16*)(W + 53477376);
    u16* ctxc  = (u16*)(W + 55443456);
    float* attnc = (float*)(W + 57409536);
    u16* VT    = (u16*)(W + 61341696);
    float* h   = (float*)(W + 28311552);
    u16* n2b   = (u16*)(W + 15728640);
    u16* mid   = (u16*)(W + 53477376);

    wconv_all<<<7489, 256, 0, stream>>>(Wq, Wk, Wv, Wo, Wm, W1, W2,
                                        WqT, WkvT, WoT, WmT, W1T, W2T,
                                        bq, bk, bv, bqs, bkv);

    const int NT = B_ * L_;
    ln_kernel<true><<<NT, 256, 0, stream>>>(x, g1, b1, Wr, br, nb, scores);
    topk_kernel<<<B_, 1024, 0, stream>>>(scores, mask, ssum, rowmap, invmap);
    pooled_part<<<dim3(8, B_), 256, 0, stream>>>(scores, nb, parts);
    pooled_wm<<<dim3(3, B_), 256, 0, stream>>>(parts, ssum, Wm, pWm);

    // dense KV projection -> Y [8192][1536]  (64 m x 12 n = 768 blocks)
    mfma_gemm<1, false, 128><<<768, 256, 0, stream>>>(nb, WkvT, bkv, Y, 1536, 768, 12,
        nullptr, nullptr, nullptr, nullptr, nullptr, nullptr, nullptr, nullptr);
    // gathered Q projection (scaled 1/8) -> qcomp [1280][768]  (20 m x 6 n = 120)
    mfma_gemm<1, true, 64><<<120, 256, 0, stream>>>(nb, WqT, bqs, qcomp, 768, 768, 6,
        nullptr, nullptr, nullptr, nullptr, nullptr, nullptr, rowmap, nullptr);
    // V transpose -> VT
    vtrans<<<dim3(32, H_, B_), 256, 0, stream>>>(Y + 768, VT, 1536);
    // compacted attention -> ctxc
    attn2<<<dim3(KPAD / 64, H_, B_), 256, 0, stream>>>(qcomp, Y, VT, ctxc);
    // attn_out (compact) = ctxc @ Wo + bo  (20 m x 6 n = 120)
    mfma_gemm<0, false, 64><<<120, 256, 0, stream>>>(ctxc, WoT, bo, attnc, 768, 768, 6,
        nullptr, nullptr, nullptr, nullptr, nullptr, nullptr, nullptr, nullptr);
    // h = x + where(mask, attnc[inv], normed@Wm + bm + s*pWm)  (128 m x 6 n = 768)
    mfma_gemm<3, false, 64><<<768, 256, 0, stream>>>(nb, WmT, bm, h, 768, 768, 6,
        x, mask, attnc, scores, pWm, nullptr, nullptr, invmap);
    // LN2 -> n2b
    ln_kernel<false><<<NT, 256, 0, stream>>>(h, g2, b2, nullptr, nullptr, n2b, nullptr);
    // FFN1 (64 m x 24 n = 1536)
    mfma_gemm<2, false, 128><<<1536, 256, 0, stream>>>(n2b, W1T, bf1, mid, 3072, 768, 24,
        nullptr, nullptr, nullptr, nullptr, nullptr, nullptr, nullptr, nullptr);
    // FFN2 (128 m x 6 n = 768)
    mfma_gemm<4, false, 64><<<768, 256, 0, stream>>>(mid, W2T, bf2, out, 768, 3072, 6,
        nullptr, nullptr, nullptr, nullptr, nullptr, h, nullptr, nullptr);
}